// Round 4
// baseline (905.616 us; speedup 1.0000x reference)
//
#include <hip/hip_runtime.h>
#include <stdint.h>

#define N_NODES 100000
#define N_EDGES 25000
#define NNZ_    800000
#define D       256
#define NTOT    (N_EDGES + N_NODES)
#define SB      1024
#define NBLK    ((NTOT + SB) / SB)
#define MP      25024                 // N_EDGES padded to 64

#define EPB 256                       // edges per ranged block
#define NPB 1024                      // nodes per ranged block
#define NEB ((N_EDGES + EPB - 1) / EPB)   // 98
#define NVB ((N_NODES + NPB - 1) / NPB)   // 98

typedef short  short8   __attribute__((ext_vector_type(8)));
typedef float  f32x4    __attribute__((ext_vector_type(4)));
typedef ushort ushortx8 __attribute__((ext_vector_type(8)));
typedef ushort ushortx4 __attribute__((ext_vector_type(4)));

__device__ __forceinline__ ushort f2bf(float f) {
    uint32_t u = __float_as_uint(f);
    uint32_t r = u + 0x7fffu + ((u >> 16) & 1u);
    return (ushort)(r >> 16);
}
__device__ __forceinline__ float bf2f(ushort u) {
    return __uint_as_float(((uint32_t)u) << 16);
}

// ---------------- dtype conversion ----------------

__global__ void __launch_bounds__(256) cvt_in(const float* __restrict__ in,
                                              ushort* __restrict__ ob, int n8) {
    int i = blockIdx.x * blockDim.x + threadIdx.x;
    if (i >= n8) return;
    const float4* p = reinterpret_cast<const float4*>(in) + (size_t)i * 2;
    float4 a = p[0], b = p[1];
    ushortx8 o;
    o[0] = f2bf(a.x); o[1] = f2bf(a.y); o[2] = f2bf(a.z); o[3] = f2bf(a.w);
    o[4] = f2bf(b.x); o[5] = f2bf(b.y); o[6] = f2bf(b.z); o[7] = f2bf(b.w);
    *(reinterpret_cast<ushortx8*>(ob) + i) = o;
}

// W[k][n] fp32 -> WT[n][k] bf16 (256x256)
__global__ void __launch_bounds__(256) cvt_wt(const float* __restrict__ W,
                                              ushort* __restrict__ WT) {
    int t = blockIdx.x * blockDim.x + threadIdx.x;
    int n = t >> 8, k = t & 255;
    WT[(size_t)n * 256 + k] = f2bf(W[(size_t)k * 256 + n]);
}

// ---------------- CSR build (range-partitioned, LDS atomics only) ----------------

// blocks [0,NEB): edge ranges over E; blocks [NEB,NEB+NVB): node ranges over V.
__global__ void __launch_bounds__(256) hist_ranged(const int* __restrict__ V,
                                                   const int* __restrict__ E,
                                                   int* __restrict__ cntC) {
    __shared__ int h[NPB];
    int b = blockIdx.x, t = threadIdx.x;
    bool eside = b < NEB;
    const int* src = eside ? E : V;
    int r0    = eside ? b * EPB : (b - NEB) * NPB;
    int bins  = eside ? EPB : NPB;
    int nmax  = eside ? N_EDGES : N_NODES;
    int obase = eside ? 0 : N_EDGES;
    for (int i = t; i < bins; i += 256) h[i] = 0;
    __syncthreads();
    for (int i = t * 4; i < NNZ_; i += 256 * 4) {
        int4 v = *reinterpret_cast<const int4*>(src + i);
        int x;
        x = v.x - r0; if ((unsigned)x < (unsigned)bins) atomicAdd(&h[x], 1);
        x = v.y - r0; if ((unsigned)x < (unsigned)bins) atomicAdd(&h[x], 1);
        x = v.z - r0; if ((unsigned)x < (unsigned)bins) atomicAdd(&h[x], 1);
        x = v.w - r0; if ((unsigned)x < (unsigned)bins) atomicAdd(&h[x], 1);
    }
    __syncthreads();
    for (int i = t; i < bins; i += 256)
        if (r0 + i < nmax) cntC[obase + r0 + i] = h[i];
}

__global__ void __launch_bounds__(256) fill_ranged(const int* __restrict__ V,
                                                   const int* __restrict__ E,
                                                   const int* __restrict__ offC,
                                                   int* __restrict__ adjAll) {
    __shared__ int cur[NPB];
    int b = blockIdx.x, t = threadIdx.x;
    bool eside = b < NEB;
    const int* key = eside ? E : V;
    const int* val = eside ? V : E;
    int r0    = eside ? b * EPB : (b - NEB) * NPB;
    int bins  = eside ? EPB : NPB;
    int obase = eside ? 0 : N_EDGES;
    for (int i = t; i < bins; i += 256) cur[i] = 0;
    __syncthreads();
    for (int i = t * 4; i < NNZ_; i += 256 * 4) {
        int4 k = *reinterpret_cast<const int4*>(key + i);
        int x;
        x = k.x - r0; if ((unsigned)x < (unsigned)bins) {
            int s = atomicAdd(&cur[x], 1); adjAll[offC[obase + k.x] + s] = val[i + 0];
        }
        x = k.y - r0; if ((unsigned)x < (unsigned)bins) {
            int s = atomicAdd(&cur[x], 1); adjAll[offC[obase + k.y] + s] = val[i + 1];
        }
        x = k.z - r0; if ((unsigned)x < (unsigned)bins) {
            int s = atomicAdd(&cur[x], 1); adjAll[offC[obase + k.z] + s] = val[i + 2];
        }
        x = k.w - r0; if ((unsigned)x < (unsigned)bins) {
            int s = atomicAdd(&cur[x], 1); adjAll[offC[obase + k.w] + s] = val[i + 3];
        }
    }
}

// ---------------- hierarchical scan ----------------

__global__ void __launch_bounds__(256) scan_bsum(const int* __restrict__ in,
                                                 int* __restrict__ bsum, int n) {
    __shared__ int sh[256];
    int b = blockIdx.x, t = threadIdx.x;
    int base = b * SB + t * 4;
    int s = 0;
    if (base + 4 <= n) {
        int4 v = *reinterpret_cast<const int4*>(in + base);
        s = v.x + v.y + v.z + v.w;
    } else {
        for (int k = 0; k < 4; ++k)
            if (base + k < n) s += in[base + k];
    }
    sh[t] = s;
    __syncthreads();
    for (int off = 128; off > 0; off >>= 1) {
        if (t < off) sh[t] += sh[t + off];
        __syncthreads();
    }
    if (t == 0) bsum[b] = sh[0];
}

__global__ void __launch_bounds__(128) scan_boff(int* __restrict__ bsum, int nb) {
    __shared__ int sh[128];
    int t = threadIdx.x;
    int v = (t < nb) ? bsum[t] : 0;
    sh[t] = v;
    __syncthreads();
    for (int off = 1; off < 128; off <<= 1) {
        int u = (t >= off) ? sh[t - off] : 0;
        __syncthreads();
        sh[t] += u;
        __syncthreads();
    }
    if (t < nb) bsum[t] = sh[t] - v;
}

__global__ void __launch_bounds__(256) scan_write(const int* __restrict__ in,
                                                  const int* __restrict__ bsum,
                                                  int* __restrict__ off, int n) {
    __shared__ int sh[256];
    int b = blockIdx.x, t = threadIdx.x;
    int base = b * SB + t * 4;
    int v0 = 0, v1 = 0, v2 = 0, v3 = 0;
    if (base + 4 <= n) {
        int4 v = *reinterpret_cast<const int4*>(in + base);
        v0 = v.x; v1 = v.y; v2 = v.z; v3 = v.w;
    } else {
        if (base + 0 < n) v0 = in[base + 0];
        if (base + 1 < n) v1 = in[base + 1];
        if (base + 2 < n) v2 = in[base + 2];
        if (base + 3 < n) v3 = in[base + 3];
    }
    int s = v0 + v1 + v2 + v3;
    sh[t] = s;
    __syncthreads();
    for (int o = 1; o < 256; o <<= 1) {
        int u = (t >= o) ? sh[t - o] : 0;
        __syncthreads();
        sh[t] += u;
        __syncthreads();
    }
    int excl = bsum[b] + sh[t] - s;
    if (base + 0 <= n) off[base + 0] = excl; excl += v0;
    if (base + 1 <= n) off[base + 1] = excl; excl += v1;
    if (base + 2 <= n) off[base + 2] = excl; excl += v2;
    if (base + 3 <= n) off[base + 3] = excl;
}

// ---------------- phase 1: edge aggregation (one wave per edge, bf16 gather) ----------------

__global__ void edge_agg(const ushort* __restrict__ Xbf, const int* __restrict__ adjAll,
                         const int* __restrict__ offC, const float* __restrict__ degE,
                         ushort* __restrict__ Ye) {
    int gid = blockIdx.x * blockDim.x + threadIdx.x;
    int edge = gid >> 6;
    int lane = gid & 63;
    if (edge >= N_EDGES) return;
    int b = offC[edge], e = offC[edge + 1];
    float a0 = 0.f, a1 = 0.f, a2 = 0.f, a3 = 0.f;
    for (int i = b; i < e; ++i) {
        int v = adjAll[i];
        ushortx4 x = *reinterpret_cast<const ushortx4*>(Xbf + (size_t)v * D + lane * 4);
        a0 += bf2f(x[0]); a1 += bf2f(x[1]); a2 += bf2f(x[2]); a3 += bf2f(x[3]);
    }
    int cnt = e - b;
    float s = degE[edge] / (float)(cnt > 1 ? cnt : 1);
    ushortx4 o;
    o[0] = f2bf(a0 * s); o[1] = f2bf(a1 * s); o[2] = f2bf(a2 * s); o[3] = f2bf(a3 * s);
    *reinterpret_cast<ushortx4*>(Ye + (size_t)edge * D + lane * 4) = o;
}

// ---------------- phase 2: MFMA GEMM  Ze[MP,256] = Ye[MP,256] @ W  (bf16, LDS-free) ----------------

__global__ void __launch_bounds__(256) gemm_mfma(const ushort* __restrict__ A,
                                                 const ushort* __restrict__ WT,
                                                 ushort* __restrict__ C, int M) {
    int wid  = threadIdx.x >> 6;
    int lane = threadIdx.x & 63;
    int row0 = blockIdx.x * 64 + wid * 16;
    int lr  = lane & 15;
    int lk8 = (lane >> 4) * 8;
    f32x4 acc[16];
#pragma unroll
    for (int t = 0; t < 16; ++t) acc[t] = (f32x4){0.f, 0.f, 0.f, 0.f};
    int arow = row0 + lr;
    if (arow >= M) arow = M - 1;
    const ushort* aptr = A + (size_t)arow * D;
#pragma unroll
    for (int k0 = 0; k0 < D; k0 += 32) {
        short8 af = *reinterpret_cast<const short8*>(aptr + k0 + lk8);
#pragma unroll
        for (int t = 0; t < 16; ++t) {
            short8 bf = *reinterpret_cast<const short8*>(
                WT + (size_t)(t * 16 + lr) * D + k0 + lk8);
            acc[t] = __builtin_amdgcn_mfma_f32_16x16x32_bf16(af, bf, acc[t], 0, 0, 0);
        }
    }
    int crow = row0 + (lane >> 4) * 4;
#pragma unroll
    for (int t = 0; t < 16; ++t) {
        int ccol = t * 16 + lr;
#pragma unroll
        for (int r = 0; r < 4; ++r) {
            int rr = crow + r;
            if (rr < M) C[(size_t)rr * D + ccol] = f2bf(acc[t][r]);
        }
    }
}

// ---------------- phase 3: node aggregation (one wave per node, bf16 gather) ----------------

__global__ void node_agg(const ushort* __restrict__ Ze, const int* __restrict__ adjAll,
                         const int* __restrict__ offC, const float* __restrict__ degV,
                         const float* __restrict__ bias, float* __restrict__ out) {
    int gid = blockIdx.x * blockDim.x + threadIdx.x;
    int node = gid >> 6;
    int lane = gid & 63;
    if (node >= N_NODES) return;
    int b = offC[N_EDGES + node], e = offC[N_EDGES + node + 1];
    float a0 = 0.f, a1 = 0.f, a2 = 0.f, a3 = 0.f;
    for (int i = b; i < e; ++i) {
        int ed = adjAll[i];
        ushortx4 z = *reinterpret_cast<const ushortx4*>(Ze + (size_t)ed * D + lane * 4);
        a0 += bf2f(z[0]); a1 += bf2f(z[1]); a2 += bf2f(z[2]); a3 += bf2f(z[3]);
    }
    float dv = degV[node];
    float4 b4 = *reinterpret_cast<const float4*>(bias + lane * 4);
    float4 o = {a0 * dv + b4.x, a1 * dv + b4.y, a2 * dv + b4.z, a3 * dv + b4.w};
    *reinterpret_cast<float4*>(out + (size_t)node * D + lane * 4) = o;
}

// ---------------- launch ----------------

extern "C" void kernel_launch(void* const* d_in, const int* in_sizes, int n_in,
                              void* d_out, int out_size, void* d_ws, size_t ws_size,
                              hipStream_t stream) {
    const float* input  = (const float*)d_in[0];
    const int*   V      = (const int*)d_in[1];
    const int*   E      = (const int*)d_in[2];
    const float* degV   = (const float*)d_in[3];
    const float* degE   = (const float*)d_in[4];
    const float* weight = (const float*)d_in[5];
    const float* bias   = (const float*)d_in[6];
    float* out = (float*)d_out;

    int* cntC   = (int*)d_ws;                       // NTOT
    int* offC   = cntC + NTOT;                      // NTOT+1
    int* bsum   = offC + (NTOT + 1);                // 128
    int* adjAll = bsum + 128;                       // 2*NNZ
    uintptr_t p = (uintptr_t)(adjAll + 2 * NNZ_);
    p = (p + 255) & ~(uintptr_t)255;
    ushort* Xbf = (ushort*)p;                       // N_NODES*D   (51.2 MB)
    ushort* Ye  = Xbf + (size_t)N_NODES * D;        // MP*D        (12.8 MB)
    ushort* Ze  = Ye + (size_t)MP * D;              // MP*D        (12.8 MB)
    ushort* WT  = Ze + (size_t)MP * D;              // 256*256     (128 KB)

    cvt_in<<<(N_NODES * D / 8 + 255) / 256, 256, 0, stream>>>(input, Xbf, N_NODES * D / 8);
    cvt_wt<<<256, 256, 0, stream>>>(weight, WT);

    hist_ranged<<<NEB + NVB, 256, 0, stream>>>(V, E, cntC);
    scan_bsum<<<NBLK, 256, 0, stream>>>(cntC, bsum, NTOT);
    scan_boff<<<1, 128, 0, stream>>>(bsum, NBLK);
    scan_write<<<NBLK, 256, 0, stream>>>(cntC, bsum, offC, NTOT);
    fill_ranged<<<NEB + NVB, 256, 0, stream>>>(V, E, offC, adjAll);

    edge_agg<<<(N_EDGES * 64 + 255) / 256, 256, 0, stream>>>(Xbf, adjAll, offC, degE, Ye);

    gemm_mfma<<<MP / 64, 256, 0, stream>>>(Ye, WT, Ze, N_EDGES);

    node_agg<<<(N_NODES * 64 + 255) / 256, 256, 0, stream>>>(Ze, adjAll, offC, degV, bias, out);
}

// Round 5
// 453.527 us; speedup vs baseline: 1.9968x; 1.9968x over previous
//
#include <hip/hip_runtime.h>
#include <stdint.h>

#define N_NODES 100000
#define N_EDGES 25000
#define NNZ_    800000
#define D       256
#define NTOT    (N_EDGES + N_NODES)
#define SB      1024
#define NBLK    ((NTOT + SB) / SB)
#define MP      25024                 // N_EDGES padded to 64

typedef short  short8   __attribute__((ext_vector_type(8)));
typedef float  f32x4    __attribute__((ext_vector_type(4)));
typedef ushort ushortx8 __attribute__((ext_vector_type(8)));
typedef ushort ushortx4 __attribute__((ext_vector_type(4)));

__device__ __forceinline__ ushort f2bf(float f) {
    uint32_t u = __float_as_uint(f);
    uint32_t r = u + 0x7fffu + ((u >> 16) & 1u);
    return (ushort)(r >> 16);
}
__device__ __forceinline__ float bf2f(ushort u) {
    return __uint_as_float(((uint32_t)u) << 16);
}

// ---------------- dtype conversion ----------------

__global__ void __launch_bounds__(256) cvt_in(const float* __restrict__ in,
                                              ushort* __restrict__ ob, int n8) {
    int i = blockIdx.x * blockDim.x + threadIdx.x;
    if (i >= n8) return;
    const float4* p = reinterpret_cast<const float4*>(in) + (size_t)i * 2;
    float4 a = p[0], b = p[1];
    ushortx8 o;
    o[0] = f2bf(a.x); o[1] = f2bf(a.y); o[2] = f2bf(a.z); o[3] = f2bf(a.w);
    o[4] = f2bf(b.x); o[5] = f2bf(b.y); o[6] = f2bf(b.z); o[7] = f2bf(b.w);
    *(reinterpret_cast<ushortx8*>(ob) + i) = o;
}

// W[k][n] fp32 -> WT[n][k] bf16 (256x256)
__global__ void __launch_bounds__(256) cvt_wt(const float* __restrict__ W,
                                              ushort* __restrict__ WT) {
    int t = blockIdx.x * blockDim.x + threadIdx.x;
    int n = t >> 8, k = t & 255;
    WT[(size_t)n * 256 + k] = f2bf(W[(size_t)k * 256 + n]);
}

// ---------------- CSR build (global atomics, 4x MLP) ----------------

__global__ void __launch_bounds__(256) hist_kernel(const int* __restrict__ V,
                                                   const int* __restrict__ E,
                                                   int* __restrict__ cntC, int n4) {
    int i = blockIdx.x * blockDim.x + threadIdx.x;
    if (i >= n4) return;
    int4 e = *reinterpret_cast<const int4*>(E + i * 4);
    int4 v = *reinterpret_cast<const int4*>(V + i * 4);
    atomicAdd(&cntC[e.x], 1);
    atomicAdd(&cntC[e.y], 1);
    atomicAdd(&cntC[e.z], 1);
    atomicAdd(&cntC[e.w], 1);
    atomicAdd(&cntC[N_EDGES + v.x], 1);
    atomicAdd(&cntC[N_EDGES + v.y], 1);
    atomicAdd(&cntC[N_EDGES + v.z], 1);
    atomicAdd(&cntC[N_EDGES + v.w], 1);
}

// ---------------- hierarchical scan ----------------

__global__ void __launch_bounds__(256) scan_bsum(const int* __restrict__ in,
                                                 int* __restrict__ bsum, int n) {
    __shared__ int sh[256];
    int b = blockIdx.x, t = threadIdx.x;
    int base = b * SB + t * 4;
    int s = 0;
    if (base + 4 <= n) {
        int4 v = *reinterpret_cast<const int4*>(in + base);
        s = v.x + v.y + v.z + v.w;
    } else {
        for (int k = 0; k < 4; ++k)
            if (base + k < n) s += in[base + k];
    }
    sh[t] = s;
    __syncthreads();
    for (int off = 128; off > 0; off >>= 1) {
        if (t < off) sh[t] += sh[t + off];
        __syncthreads();
    }
    if (t == 0) bsum[b] = sh[0];
}

__global__ void __launch_bounds__(128) scan_boff(int* __restrict__ bsum, int nb) {
    __shared__ int sh[128];
    int t = threadIdx.x;
    int v = (t < nb) ? bsum[t] : 0;
    sh[t] = v;
    __syncthreads();
    for (int off = 1; off < 128; off <<= 1) {
        int u = (t >= off) ? sh[t - off] : 0;
        __syncthreads();
        sh[t] += u;
        __syncthreads();
    }
    if (t < nb) bsum[t] = sh[t] - v;
}

// writes offC[0..n] AND curC[0..n-1] (= offC, the running fill cursor)
__global__ void __launch_bounds__(256) scan_write(const int* __restrict__ in,
                                                  const int* __restrict__ bsum,
                                                  int* __restrict__ off,
                                                  int* __restrict__ cur, int n) {
    __shared__ int sh[256];
    int b = blockIdx.x, t = threadIdx.x;
    int base = b * SB + t * 4;
    int v0 = 0, v1 = 0, v2 = 0, v3 = 0;
    if (base + 4 <= n) {
        int4 v = *reinterpret_cast<const int4*>(in + base);
        v0 = v.x; v1 = v.y; v2 = v.z; v3 = v.w;
    } else {
        if (base + 0 < n) v0 = in[base + 0];
        if (base + 1 < n) v1 = in[base + 1];
        if (base + 2 < n) v2 = in[base + 2];
        if (base + 3 < n) v3 = in[base + 3];
    }
    int s = v0 + v1 + v2 + v3;
    sh[t] = s;
    __syncthreads();
    for (int o = 1; o < 256; o <<= 1) {
        int u = (t >= o) ? sh[t - o] : 0;
        __syncthreads();
        sh[t] += u;
        __syncthreads();
    }
    int excl = bsum[b] + sh[t] - s;
    if (base + 0 <= n) { off[base + 0] = excl; if (base + 0 < n) cur[base + 0] = excl; } excl += v0;
    if (base + 1 <= n) { off[base + 1] = excl; if (base + 1 < n) cur[base + 1] = excl; } excl += v1;
    if (base + 2 <= n) { off[base + 2] = excl; if (base + 2 < n) cur[base + 2] = excl; } excl += v2;
    if (base + 3 <= n) { off[base + 3] = excl; if (base + 3 < n) cur[base + 3] = excl; }
}

// slot = atomicAdd(cur[key]); adjAll[slot] = val   (2 random ops per side)
__global__ void __launch_bounds__(256) fill_kernel(const int* __restrict__ V,
                                                   const int* __restrict__ E,
                                                   int* __restrict__ curC,
                                                   int* __restrict__ adjAll, int n4) {
    int i = blockIdx.x * blockDim.x + threadIdx.x;
    if (i >= n4) return;
    int4 e = *reinterpret_cast<const int4*>(E + i * 4);
    int4 v = *reinterpret_cast<const int4*>(V + i * 4);
    int s0 = atomicAdd(&curC[e.x], 1);
    int s1 = atomicAdd(&curC[e.y], 1);
    int s2 = atomicAdd(&curC[e.z], 1);
    int s3 = atomicAdd(&curC[e.w], 1);
    int t0 = atomicAdd(&curC[N_EDGES + v.x], 1);
    int t1 = atomicAdd(&curC[N_EDGES + v.y], 1);
    int t2 = atomicAdd(&curC[N_EDGES + v.z], 1);
    int t3 = atomicAdd(&curC[N_EDGES + v.w], 1);
    adjAll[s0] = v.x; adjAll[s1] = v.y; adjAll[s2] = v.z; adjAll[s3] = v.w;
    adjAll[t0] = e.x; adjAll[t1] = e.y; adjAll[t2] = e.z; adjAll[t3] = e.w;
}

// ---------------- phase 1: edge aggregation (one wave per edge, bf16 gather) ----------------

__global__ void edge_agg(const ushort* __restrict__ Xbf, const int* __restrict__ adjAll,
                         const int* __restrict__ offC, const float* __restrict__ degE,
                         ushort* __restrict__ Ye) {
    int gid = blockIdx.x * blockDim.x + threadIdx.x;
    int edge = gid >> 6;
    int lane = gid & 63;
    if (edge >= N_EDGES) return;
    int b = offC[edge], e = offC[edge + 1];
    float a0 = 0.f, a1 = 0.f, a2 = 0.f, a3 = 0.f;
    for (int i = b; i < e; ++i) {
        int v = adjAll[i];
        ushortx4 x = *reinterpret_cast<const ushortx4*>(Xbf + (size_t)v * D + lane * 4);
        a0 += bf2f(x[0]); a1 += bf2f(x[1]); a2 += bf2f(x[2]); a3 += bf2f(x[3]);
    }
    int cnt = e - b;
    float s = degE[edge] / (float)(cnt > 1 ? cnt : 1);
    ushortx4 o;
    o[0] = f2bf(a0 * s); o[1] = f2bf(a1 * s); o[2] = f2bf(a2 * s); o[3] = f2bf(a3 * s);
    *reinterpret_cast<ushortx4*>(Ye + (size_t)edge * D + lane * 4) = o;
}

// ---------------- phase 2: MFMA GEMM  Ze[MP,256] = Ye[MP,256] @ W  (bf16, LDS-free) ----------------

__global__ void __launch_bounds__(256) gemm_mfma(const ushort* __restrict__ A,
                                                 const ushort* __restrict__ WT,
                                                 ushort* __restrict__ C, int M) {
    int wid  = threadIdx.x >> 6;
    int lane = threadIdx.x & 63;
    int row0 = blockIdx.x * 64 + wid * 16;
    int lr  = lane & 15;
    int lk8 = (lane >> 4) * 8;
    f32x4 acc[16];
#pragma unroll
    for (int t = 0; t < 16; ++t) acc[t] = (f32x4){0.f, 0.f, 0.f, 0.f};
    int arow = row0 + lr;
    if (arow >= M) arow = M - 1;
    const ushort* aptr = A + (size_t)arow * D;
#pragma unroll
    for (int k0 = 0; k0 < D; k0 += 32) {
        short8 af = *reinterpret_cast<const short8*>(aptr + k0 + lk8);
#pragma unroll
        for (int t = 0; t < 16; ++t) {
            short8 bf = *reinterpret_cast<const short8*>(
                WT + (size_t)(t * 16 + lr) * D + k0 + lk8);
            acc[t] = __builtin_amdgcn_mfma_f32_16x16x32_bf16(af, bf, acc[t], 0, 0, 0);
        }
    }
    int crow = row0 + (lane >> 4) * 4;
#pragma unroll
    for (int t = 0; t < 16; ++t) {
        int ccol = t * 16 + lr;
#pragma unroll
        for (int r = 0; r < 4; ++r) {
            int rr = crow + r;
            if (rr < M) C[(size_t)rr * D + ccol] = f2bf(acc[t][r]);
        }
    }
}

// ---------------- phase 3: node aggregation (one wave per node, bf16 gather) ----------------

__global__ void node_agg(const ushort* __restrict__ Ze, const int* __restrict__ adjAll,
                         const int* __restrict__ offC, const float* __restrict__ degV,
                         const float* __restrict__ bias, float* __restrict__ out) {
    int gid = blockIdx.x * blockDim.x + threadIdx.x;
    int node = gid >> 6;
    int lane = gid & 63;
    if (node >= N_NODES) return;
    int b = offC[N_EDGES + node], e = offC[N_EDGES + node + 1];
    float a0 = 0.f, a1 = 0.f, a2 = 0.f, a3 = 0.f;
    for (int i = b; i < e; ++i) {
        int ed = adjAll[i];
        ushortx4 z = *reinterpret_cast<const ushortx4*>(Ze + (size_t)ed * D + lane * 4);
        a0 += bf2f(z[0]); a1 += bf2f(z[1]); a2 += bf2f(z[2]); a3 += bf2f(z[3]);
    }
    float dv = degV[node];
    float4 b4 = *reinterpret_cast<const float4*>(bias + lane * 4);
    float4 o = {a0 * dv + b4.x, a1 * dv + b4.y, a2 * dv + b4.z, a3 * dv + b4.w};
    *reinterpret_cast<float4*>(out + (size_t)node * D + lane * 4) = o;
}

// ---------------- launch ----------------

extern "C" void kernel_launch(void* const* d_in, const int* in_sizes, int n_in,
                              void* d_out, int out_size, void* d_ws, size_t ws_size,
                              hipStream_t stream) {
    const float* input  = (const float*)d_in[0];
    const int*   V      = (const int*)d_in[1];
    const int*   E      = (const int*)d_in[2];
    const float* degV   = (const float*)d_in[3];
    const float* degE   = (const float*)d_in[4];
    const float* weight = (const float*)d_in[5];
    const float* bias   = (const float*)d_in[6];
    float* out = (float*)d_out;

    int* cntC   = (int*)d_ws;                       // NTOT
    int* curC   = cntC + NTOT;                      // NTOT
    int* offC   = curC + NTOT;                      // NTOT+1
    int* bsum   = offC + (NTOT + 1);                // 128
    int* adjAll = bsum + 128;                       // 2*NNZ
    uintptr_t p = (uintptr_t)(adjAll + 2 * NNZ_);
    p = (p + 255) & ~(uintptr_t)255;
    ushort* Xbf = (ushort*)p;                       // N_NODES*D   (51.2 MB)
    ushort* Ye  = Xbf + (size_t)N_NODES * D;        // MP*D        (12.8 MB)
    ushort* Ze  = Ye + (size_t)MP * D;              // MP*D        (12.8 MB)
    ushort* WT  = Ze + (size_t)MP * D;              // 256*256     (128 KB)

    hipMemsetAsync(cntC, 0, (size_t)NTOT * sizeof(int), stream);

    cvt_in<<<(N_NODES * D / 8 + 255) / 256, 256, 0, stream>>>(input, Xbf, N_NODES * D / 8);
    cvt_wt<<<256, 256, 0, stream>>>(weight, WT);

    hist_kernel<<<(NNZ_ / 4 + 255) / 256, 256, 0, stream>>>(V, E, cntC, NNZ_ / 4);
    scan_bsum<<<NBLK, 256, 0, stream>>>(cntC, bsum, NTOT);
    scan_boff<<<1, 128, 0, stream>>>(bsum, NBLK);
    scan_write<<<NBLK, 256, 0, stream>>>(cntC, bsum, offC, curC, NTOT);
    fill_kernel<<<(NNZ_ / 4 + 255) / 256, 256, 0, stream>>>(V, E, curC, adjAll, NNZ_ / 4);

    edge_agg<<<(N_EDGES * 64 + 255) / 256, 256, 0, stream>>>(Xbf, adjAll, offC, degE, Ye);

    gemm_mfma<<<MP / 64, 256, 0, stream>>>(Ye, WT, Ze, N_EDGES);

    node_agg<<<(N_NODES * 64 + 255) / 256, 256, 0, stream>>>(Ze, adjAll, offC, degV, bias, out);
}

// Round 6
// 396.989 us; speedup vs baseline: 2.2812x; 1.1424x over previous
//
#include <hip/hip_runtime.h>
#include <stdint.h>

#define N_NODES 100000
#define N_EDGES 25000
#define NNZ_    800000
#define D       256
#define NTOT    (N_EDGES + N_NODES)
#define SB      1024
#define NBLK    ((NTOT + SB) / SB)
#define MP      25024                 // N_EDGES padded to 64

#define HB ((NNZ_ / 4 + 255) / 256)        // 782 hist blocks
#define WB 256                              // cvt_wt blocks (256x256 elems)
#define CB ((N_NODES * D / 8 + 255) / 256)  // 12500 cvt_in blocks

typedef short  short8   __attribute__((ext_vector_type(8)));
typedef float  f32x4    __attribute__((ext_vector_type(4)));
typedef ushort ushortx8 __attribute__((ext_vector_type(8)));
typedef ushort ushortx4 __attribute__((ext_vector_type(4)));

__device__ __forceinline__ ushort f2bf(float f) {
    uint32_t u = __float_as_uint(f);
    uint32_t r = u + 0x7fffu + ((u >> 16) & 1u);
    return (ushort)(r >> 16);
}
__device__ __forceinline__ float bf2f(ushort u) {
    return __uint_as_float(((uint32_t)u) << 16);
}

// ---------------- fused front: hist (atomics) + cvt_wt + cvt_in (streaming) ----------------

__global__ void __launch_bounds__(256) front_kernel(const int* __restrict__ V,
                                                    const int* __restrict__ E,
                                                    int* __restrict__ cntC,
                                                    const float* __restrict__ W,
                                                    ushort* __restrict__ WT,
                                                    const float* __restrict__ in,
                                                    ushort* __restrict__ Xbf) {
    int b = blockIdx.x, t = threadIdx.x;
    if (b < HB) {
        // histogram over E and V, 4 items/thread
        int i = b * 256 + t;
        if (i >= NNZ_ / 4) return;
        int4 e = *reinterpret_cast<const int4*>(E + i * 4);
        int4 v = *reinterpret_cast<const int4*>(V + i * 4);
        atomicAdd(&cntC[e.x], 1);
        atomicAdd(&cntC[e.y], 1);
        atomicAdd(&cntC[e.z], 1);
        atomicAdd(&cntC[e.w], 1);
        atomicAdd(&cntC[N_EDGES + v.x], 1);
        atomicAdd(&cntC[N_EDGES + v.y], 1);
        atomicAdd(&cntC[N_EDGES + v.z], 1);
        atomicAdd(&cntC[N_EDGES + v.w], 1);
    } else if (b < HB + WB) {
        // W[k][n] fp32 -> WT[n][k] bf16
        int g = (b - HB) * 256 + t;
        int n = g >> 8, k = g & 255;
        WT[(size_t)n * 256 + k] = f2bf(W[(size_t)k * 256 + n]);
    } else {
        // input fp32 -> bf16, 8 elems/thread
        int i = (b - HB - WB) * 256 + t;
        if (i >= N_NODES * D / 8) return;
        const float4* p = reinterpret_cast<const float4*>(in) + (size_t)i * 2;
        float4 a = p[0], c = p[1];
        ushortx8 o;
        o[0] = f2bf(a.x); o[1] = f2bf(a.y); o[2] = f2bf(a.z); o[3] = f2bf(a.w);
        o[4] = f2bf(c.x); o[5] = f2bf(c.y); o[6] = f2bf(c.z); o[7] = f2bf(c.w);
        *(reinterpret_cast<ushortx8*>(Xbf) + i) = o;
    }
}

// ---------------- hierarchical scan ----------------

__global__ void __launch_bounds__(256) scan_bsum(const int* __restrict__ in,
                                                 int* __restrict__ bsum, int n) {
    __shared__ int sh[256];
    int b = blockIdx.x, t = threadIdx.x;
    int base = b * SB + t * 4;
    int s = 0;
    if (base + 4 <= n) {
        int4 v = *reinterpret_cast<const int4*>(in + base);
        s = v.x + v.y + v.z + v.w;
    } else {
        for (int k = 0; k < 4; ++k)
            if (base + k < n) s += in[base + k];
    }
    sh[t] = s;
    __syncthreads();
    for (int off = 128; off > 0; off >>= 1) {
        if (t < off) sh[t] += sh[t + off];
        __syncthreads();
    }
    if (t == 0) bsum[b] = sh[0];
}

__global__ void __launch_bounds__(128) scan_boff(int* __restrict__ bsum, int nb) {
    __shared__ int sh[128];
    int t = threadIdx.x;
    int v = (t < nb) ? bsum[t] : 0;
    sh[t] = v;
    __syncthreads();
    for (int off = 1; off < 128; off <<= 1) {
        int u = (t >= off) ? sh[t - off] : 0;
        __syncthreads();
        sh[t] += u;
        __syncthreads();
    }
    if (t < nb) bsum[t] = sh[t] - v;
}

// writes offC[0..n] AND curC[0..n-1] (running fill cursor)
__global__ void __launch_bounds__(256) scan_write(const int* __restrict__ in,
                                                  const int* __restrict__ bsum,
                                                  int* __restrict__ off,
                                                  int* __restrict__ cur, int n) {
    __shared__ int sh[256];
    int b = blockIdx.x, t = threadIdx.x;
    int base = b * SB + t * 4;
    int v0 = 0, v1 = 0, v2 = 0, v3 = 0;
    if (base + 4 <= n) {
        int4 v = *reinterpret_cast<const int4*>(in + base);
        v0 = v.x; v1 = v.y; v2 = v.z; v3 = v.w;
    } else {
        if (base + 0 < n) v0 = in[base + 0];
        if (base + 1 < n) v1 = in[base + 1];
        if (base + 2 < n) v2 = in[base + 2];
        if (base + 3 < n) v3 = in[base + 3];
    }
    int s = v0 + v1 + v2 + v3;
    sh[t] = s;
    __syncthreads();
    for (int o = 1; o < 256; o <<= 1) {
        int u = (t >= o) ? sh[t - o] : 0;
        __syncthreads();
        sh[t] += u;
        __syncthreads();
    }
    int excl = bsum[b] + sh[t] - s;
    if (base + 0 <= n) { off[base + 0] = excl; if (base + 0 < n) cur[base + 0] = excl; } excl += v0;
    if (base + 1 <= n) { off[base + 1] = excl; if (base + 1 < n) cur[base + 1] = excl; } excl += v1;
    if (base + 2 <= n) { off[base + 2] = excl; if (base + 2 < n) cur[base + 2] = excl; } excl += v2;
    if (base + 3 <= n) { off[base + 3] = excl; if (base + 3 < n) cur[base + 3] = excl; }
}

__global__ void __launch_bounds__(256) fill_kernel(const int* __restrict__ V,
                                                   const int* __restrict__ E,
                                                   int* __restrict__ curC,
                                                   int* __restrict__ adjAll, int n4) {
    int i = blockIdx.x * blockDim.x + threadIdx.x;
    if (i >= n4) return;
    int4 e = *reinterpret_cast<const int4*>(E + i * 4);
    int4 v = *reinterpret_cast<const int4*>(V + i * 4);
    int s0 = atomicAdd(&curC[e.x], 1);
    int s1 = atomicAdd(&curC[e.y], 1);
    int s2 = atomicAdd(&curC[e.z], 1);
    int s3 = atomicAdd(&curC[e.w], 1);
    int t0 = atomicAdd(&curC[N_EDGES + v.x], 1);
    int t1 = atomicAdd(&curC[N_EDGES + v.y], 1);
    int t2 = atomicAdd(&curC[N_EDGES + v.z], 1);
    int t3 = atomicAdd(&curC[N_EDGES + v.w], 1);
    adjAll[s0] = v.x; adjAll[s1] = v.y; adjAll[s2] = v.z; adjAll[s3] = v.w;
    adjAll[t0] = e.x; adjAll[t1] = e.y; adjAll[t2] = e.z; adjAll[t3] = e.w;
}

// ---------------- phase 1: edge aggregation (one wave per edge, dual-row 16B/lane) ----------------

__global__ void edge_agg(const ushort* __restrict__ Xbf, const int* __restrict__ adjAll,
                         const int* __restrict__ offC, const float* __restrict__ degE,
                         ushort* __restrict__ Ye) {
    int gid = blockIdx.x * blockDim.x + threadIdx.x;
    int edge = gid >> 6;
    int lane = gid & 63;
    if (edge >= N_EDGES) return;
    int half = lane >> 5;
    int col8 = (lane & 31) * 8;
    int b = offC[edge], e = offC[edge + 1];
    float a[8] = {0.f, 0.f, 0.f, 0.f, 0.f, 0.f, 0.f, 0.f};
    for (int i = b; i < e; i += 2) {
        int i2 = i + half;
        bool valid = i2 < e;
        int row = adjAll[valid ? i2 : i];
        ushortx8 x = *reinterpret_cast<const ushortx8*>(Xbf + (size_t)row * D + col8);
        if (valid) {
#pragma unroll
            for (int k = 0; k < 8; ++k) a[k] += bf2f(x[k]);
        }
    }
#pragma unroll
    for (int k = 0; k < 8; ++k) a[k] += __shfl_xor(a[k], 32, 64);
    int cnt = e - b;
    float s = degE[edge] / (float)(cnt > 1 ? cnt : 1);
    int k0 = half * 4;
    ushortx4 o;
    o[0] = f2bf(a[k0 + 0] * s); o[1] = f2bf(a[k0 + 1] * s);
    o[2] = f2bf(a[k0 + 2] * s); o[3] = f2bf(a[k0 + 3] * s);
    *reinterpret_cast<ushortx4*>(Ye + (size_t)edge * D + col8 + k0) = o;
}

// ---------------- phase 2: MFMA GEMM  Ze[MP,256] = Ye[MP,256] @ W  (bf16, LDS-free) ----------------

__global__ void __launch_bounds__(256) gemm_mfma(const ushort* __restrict__ A,
                                                 const ushort* __restrict__ WT,
                                                 ushort* __restrict__ C, int M) {
    int wid  = threadIdx.x >> 6;
    int lane = threadIdx.x & 63;
    int row0 = blockIdx.x * 64 + wid * 16;
    int lr  = lane & 15;
    int lk8 = (lane >> 4) * 8;
    f32x4 acc[16];
#pragma unroll
    for (int t = 0; t < 16; ++t) acc[t] = (f32x4){0.f, 0.f, 0.f, 0.f};
    int arow = row0 + lr;
    if (arow >= M) arow = M - 1;
    const ushort* aptr = A + (size_t)arow * D;
#pragma unroll
    for (int k0 = 0; k0 < D; k0 += 32) {
        short8 af = *reinterpret_cast<const short8*>(aptr + k0 + lk8);
#pragma unroll
        for (int t = 0; t < 16; ++t) {
            short8 bf = *reinterpret_cast<const short8*>(
                WT + (size_t)(t * 16 + lr) * D + k0 + lk8);
            acc[t] = __builtin_amdgcn_mfma_f32_16x16x32_bf16(af, bf, acc[t], 0, 0, 0);
        }
    }
    int crow = row0 + (lane >> 4) * 4;
#pragma unroll
    for (int t = 0; t < 16; ++t) {
        int ccol = t * 16 + lr;
#pragma unroll
        for (int r = 0; r < 4; ++r) {
            int rr = crow + r;
            if (rr < M) C[(size_t)rr * D + ccol] = f2bf(acc[t][r]);
        }
    }
}

// ---------------- phase 3: node aggregation (one wave per node, dual-row 16B/lane) ----------------

__global__ void node_agg(const ushort* __restrict__ Ze, const int* __restrict__ adjAll,
                         const int* __restrict__ offC, const float* __restrict__ degV,
                         const float* __restrict__ bias, float* __restrict__ out) {
    int gid = blockIdx.x * blockDim.x + threadIdx.x;
    int node = gid >> 6;
    int lane = gid & 63;
    if (node >= N_NODES) return;
    int half = lane >> 5;
    int col8 = (lane & 31) * 8;
    int b = offC[N_EDGES + node], e = offC[N_EDGES + node + 1];
    float a[8] = {0.f, 0.f, 0.f, 0.f, 0.f, 0.f, 0.f, 0.f};
    for (int i = b; i < e; i += 2) {
        int i2 = i + half;
        bool valid = i2 < e;
        int row = adjAll[valid ? i2 : i];
        ushortx8 z = *reinterpret_cast<const ushortx8*>(Ze + (size_t)row * D + col8);
        if (valid) {
#pragma unroll
            for (int k = 0; k < 8; ++k) a[k] += bf2f(z[k]);
        }
    }
#pragma unroll
    for (int k = 0; k < 8; ++k) a[k] += __shfl_xor(a[k], 32, 64);
    float dv = degV[node];
    int k0 = half * 4;
    int c = col8 + k0;
    float4 b4 = *reinterpret_cast<const float4*>(bias + c);
    float4 o = {a[k0 + 0] * dv + b4.x, a[k0 + 1] * dv + b4.y,
                a[k0 + 2] * dv + b4.z, a[k0 + 3] * dv + b4.w};
    *reinterpret_cast<float4*>(out + (size_t)node * D + c) = o;
}

// ---------------- launch ----------------

extern "C" void kernel_launch(void* const* d_in, const int* in_sizes, int n_in,
                              void* d_out, int out_size, void* d_ws, size_t ws_size,
                              hipStream_t stream) {
    const float* input  = (const float*)d_in[0];
    const int*   V      = (const int*)d_in[1];
    const int*   E      = (const int*)d_in[2];
    const float* degV   = (const float*)d_in[3];
    const float* degE   = (const float*)d_in[4];
    const float* weight = (const float*)d_in[5];
    const float* bias   = (const float*)d_in[6];
    float* out = (float*)d_out;

    int* cntC   = (int*)d_ws;                       // NTOT
    int* curC   = cntC + NTOT;                      // NTOT
    int* offC   = curC + NTOT;                      // NTOT+1
    int* bsum   = offC + (NTOT + 1);                // 128
    int* adjAll = bsum + 128;                       // 2*NNZ
    uintptr_t p = (uintptr_t)(adjAll + 2 * NNZ_);
    p = (p + 255) & ~(uintptr_t)255;
    ushort* Xbf = (ushort*)p;                       // N_NODES*D   (51.2 MB)
    ushort* Ye  = Xbf + (size_t)N_NODES * D;        // MP*D        (12.8 MB)
    ushort* Ze  = Ye + (size_t)MP * D;              // MP*D        (12.8 MB)
    ushort* WT  = Ze + (size_t)MP * D;              // 256*256     (128 KB)

    hipMemsetAsync(cntC, 0, (size_t)NTOT * sizeof(int), stream);

    front_kernel<<<HB + WB + CB, 256, 0, stream>>>(V, E, cntC, weight, WT, input, Xbf);

    scan_bsum<<<NBLK, 256, 0, stream>>>(cntC, bsum, NTOT);
    scan_boff<<<1, 128, 0, stream>>>(bsum, NBLK);
    scan_write<<<NBLK, 256, 0, stream>>>(cntC, bsum, offC, curC, NTOT);
    fill_kernel<<<(NNZ_ / 4 + 255) / 256, 256, 0, stream>>>(V, E, curC, adjAll, NNZ_ / 4);

    edge_agg<<<(N_EDGES * 64 + 255) / 256, 256, 0, stream>>>(Xbf, adjAll, offC, degE, Ye);

    gemm_mfma<<<MP / 64, 256, 0, stream>>>(Ye, WT, Ze, N_EDGES);

    node_agg<<<(N_NODES * 64 + 255) / 256, 256, 0, stream>>>(Ze, adjAll, offC, degV, bias, out);
}

// Round 7
// 272.999 us; speedup vs baseline: 3.3173x; 1.4542x over previous
//
#include <hip/hip_runtime.h>
#include <stdint.h>

#define N_NODES 100000
#define N_EDGES 25000
#define NNZ_    800000
#define D       256
#define NTOT    (N_EDGES + N_NODES)
#define SB      1024
#define NBLK    ((NTOT + SB) / SB)
#define MP      25024                 // N_EDGES padded to 64

// bucketed CSR build
#define SHE   9                       // edge keys per bucket = 512
#define SHV   11                      // node keys per bucket = 2048
#define WKE   512
#define WKV   2048
#define NBKE  ((N_EDGES + WKE - 1) / WKE)   // 49
#define NBKV  ((N_NODES + WKV - 1) / WKV)   // 49
#define NB    (NBKE + NBKV)                 // 98
#define CAP   24576                   // pairs capacity per bucket (mean 16384, sigma ~127)

#define WB 256                              // cvt_wt blocks
#define CB ((N_NODES * D / 8 + 255) / 256)  // cvt_in blocks

typedef short  short8   __attribute__((ext_vector_type(8)));
typedef float  f32x4    __attribute__((ext_vector_type(4)));
typedef ushort ushortx8 __attribute__((ext_vector_type(8)));
typedef ushort ushortx4 __attribute__((ext_vector_type(4)));

__device__ __forceinline__ ushort f2bf(float f) {
    uint32_t u = __float_as_uint(f);
    uint32_t r = u + 0x7fffu + ((u >> 16) & 1u);
    return (ushort)(r >> 16);
}
__device__ __forceinline__ float bf2f(ushort u) {
    return __uint_as_float(((uint32_t)u) << 16);
}

// ---------------- fused front: cvt_wt + cvt_in (streaming) ----------------

__global__ void __launch_bounds__(256) front_kernel(const float* __restrict__ W,
                                                    ushort* __restrict__ WT,
                                                    const float* __restrict__ in,
                                                    ushort* __restrict__ Xbf) {
    int b = blockIdx.x, t = threadIdx.x;
    if (b < WB) {
        int g = b * 256 + t;
        int n = g >> 8, k = g & 255;
        WT[(size_t)n * 256 + k] = f2bf(W[(size_t)k * 256 + n]);
    } else {
        int i = (b - WB) * 256 + t;
        if (i >= N_NODES * D / 8) return;
        const float4* p = reinterpret_cast<const float4*>(in) + (size_t)i * 2;
        float4 a = p[0], c = p[1];
        ushortx8 o;
        o[0] = f2bf(a.x); o[1] = f2bf(a.y); o[2] = f2bf(a.z); o[3] = f2bf(a.w);
        o[4] = f2bf(c.x); o[5] = f2bf(c.y); o[6] = f2bf(c.z); o[7] = f2bf(c.w);
        *(reinterpret_cast<ushortx8*>(Xbf) + i) = o;
    }
}

// ---------------- pass 1: bucket scatter (block-reserve, burst writes) ----------------

__global__ void __launch_bounds__(256) scatter1(const int* __restrict__ V,
                                                const int* __restrict__ E,
                                                int* __restrict__ gcur,
                                                int2* __restrict__ pairs) {
    __shared__ int cnt[NB], base[NB], lcur[NB];
    int t = threadIdx.x;
    for (int j = t; j < NB; j += 256) cnt[j] = 0;
    __syncthreads();
    int i0 = (blockIdx.x * 256 + t) * 16;
    bool act = i0 < NNZ_;
    if (act) {
#pragma unroll
        for (int c = 0; c < 16; c += 4) {
            int4 e = *reinterpret_cast<const int4*>(E + i0 + c);
            int4 v = *reinterpret_cast<const int4*>(V + i0 + c);
            atomicAdd(&cnt[e.x >> SHE], 1);
            atomicAdd(&cnt[e.y >> SHE], 1);
            atomicAdd(&cnt[e.z >> SHE], 1);
            atomicAdd(&cnt[e.w >> SHE], 1);
            atomicAdd(&cnt[NBKE + (v.x >> SHV)], 1);
            atomicAdd(&cnt[NBKE + (v.y >> SHV)], 1);
            atomicAdd(&cnt[NBKE + (v.z >> SHV)], 1);
            atomicAdd(&cnt[NBKE + (v.w >> SHV)], 1);
        }
    }
    __syncthreads();
    for (int j = t; j < NB; j += 256) {
        int c = cnt[j];
        base[j] = c ? atomicAdd(&gcur[j], c) : 0;
        lcur[j] = 0;
    }
    __syncthreads();
    if (act) {
#pragma unroll
        for (int c = 0; c < 16; c += 4) {
            int4 e = *reinterpret_cast<const int4*>(E + i0 + c);
            int4 v = *reinterpret_cast<const int4*>(V + i0 + c);
            int ev[4] = {e.x, e.y, e.z, e.w};
            int vv[4] = {v.x, v.y, v.z, v.w};
#pragma unroll
            for (int k = 0; k < 4; ++k) {
                int b1 = ev[k] >> SHE;
                int p1 = base[b1] + atomicAdd(&lcur[b1], 1);
                if (p1 < CAP) pairs[(size_t)b1 * CAP + p1] = make_int2(ev[k], vv[k]);
                int b2 = NBKE + (vv[k] >> SHV);
                int p2 = base[b2] + atomicAdd(&lcur[b2], 1);
                if (p2 < CAP) pairs[(size_t)b2 * CAP + p2] = make_int2(vv[k], ev[k]);
            }
        }
    }
}

// ---------------- pass 2: per-bucket LDS histogram -> coalesced counts ----------------

__global__ void __launch_bounds__(256) count2(const int2* __restrict__ pairs,
                                              const int* __restrict__ gcur,
                                              int* __restrict__ cntC) {
    __shared__ int hist[WKV];
    int b = blockIdx.x, t = threadIdx.x;
    bool eside = b < NBKE;
    int kb    = eside ? b * WKE : (b - NBKE) * WKV;
    int wk    = eside ? WKE : WKV;
    int nk    = eside ? min(WKE, N_EDGES - kb) : min(WKV, N_NODES - kb);
    int obase = eside ? kb : N_EDGES + kb;
    for (int j = t; j < wk; j += 256) hist[j] = 0;
    __syncthreads();
    int n = min(gcur[b], CAP);
    const int2* p = pairs + (size_t)b * CAP;
    for (int i = t; i < n; i += 256) {
        int2 pr = p[i];
        atomicAdd(&hist[pr.x - kb], 1);
    }
    __syncthreads();
    for (int j = t; j < nk; j += 256) cntC[obase + j] = hist[j];
}

// ---------------- hierarchical scan ----------------

__global__ void __launch_bounds__(256) scan_bsum(const int* __restrict__ in,
                                                 int* __restrict__ bsum, int n) {
    __shared__ int sh[256];
    int b = blockIdx.x, t = threadIdx.x;
    int base = b * SB + t * 4;
    int s = 0;
    if (base + 4 <= n) {
        int4 v = *reinterpret_cast<const int4*>(in + base);
        s = v.x + v.y + v.z + v.w;
    } else {
        for (int k = 0; k < 4; ++k)
            if (base + k < n) s += in[base + k];
    }
    sh[t] = s;
    __syncthreads();
    for (int off = 128; off > 0; off >>= 1) {
        if (t < off) sh[t] += sh[t + off];
        __syncthreads();
    }
    if (t == 0) bsum[b] = sh[0];
}

__global__ void __launch_bounds__(128) scan_boff(int* __restrict__ bsum, int nb) {
    __shared__ int sh[128];
    int t = threadIdx.x;
    int v = (t < nb) ? bsum[t] : 0;
    sh[t] = v;
    __syncthreads();
    for (int off = 1; off < 128; off <<= 1) {
        int u = (t >= off) ? sh[t - off] : 0;
        __syncthreads();
        sh[t] += u;
        __syncthreads();
    }
    if (t < nb) bsum[t] = sh[t] - v;
}

__global__ void __launch_bounds__(256) scan_write(const int* __restrict__ in,
                                                  const int* __restrict__ bsum,
                                                  int* __restrict__ off, int n) {
    __shared__ int sh[256];
    int b = blockIdx.x, t = threadIdx.x;
    int base = b * SB + t * 4;
    int v0 = 0, v1 = 0, v2 = 0, v3 = 0;
    if (base + 4 <= n) {
        int4 v = *reinterpret_cast<const int4*>(in + base);
        v0 = v.x; v1 = v.y; v2 = v.z; v3 = v.w;
    } else {
        if (base + 0 < n) v0 = in[base + 0];
        if (base + 1 < n) v1 = in[base + 1];
        if (base + 2 < n) v2 = in[base + 2];
        if (base + 3 < n) v3 = in[base + 3];
    }
    int s = v0 + v1 + v2 + v3;
    sh[t] = s;
    __syncthreads();
    for (int o = 1; o < 256; o <<= 1) {
        int u = (t >= o) ? sh[t - o] : 0;
        __syncthreads();
        sh[t] += u;
        __syncthreads();
    }
    int excl = bsum[b] + sh[t] - s;
    if (base + 0 <= n) off[base + 0] = excl; excl += v0;
    if (base + 1 <= n) off[base + 1] = excl; excl += v1;
    if (base + 2 <= n) off[base + 2] = excl; excl += v2;
    if (base + 3 <= n) off[base + 3] = excl;
}

// ---------------- pass 3: per-bucket fill (LDS cursors, windowed writes) ----------------

__global__ void __launch_bounds__(256) fill3(const int2* __restrict__ pairs,
                                             const int* __restrict__ gcur,
                                             const int* __restrict__ offC,
                                             int* __restrict__ adjAll) {
    __shared__ int cur[WKV];
    int b = blockIdx.x, t = threadIdx.x;
    bool eside = b < NBKE;
    int kb    = eside ? b * WKE : (b - NBKE) * WKV;
    int nk    = eside ? min(WKE, N_EDGES - kb) : min(WKV, N_NODES - kb);
    int obase = eside ? kb : N_EDGES + kb;
    for (int j = t; j < nk; j += 256) cur[j] = offC[obase + j];
    __syncthreads();
    int n = min(gcur[b], CAP);
    const int2* p = pairs + (size_t)b * CAP;
    for (int i = t; i < n; i += 256) {
        int2 pr = p[i];
        int slot = atomicAdd(&cur[pr.x - kb], 1);
        adjAll[slot] = pr.y;
    }
}

// ---------------- phase 1: edge aggregation (one wave per edge, dual-row 16B/lane) ----------------

__global__ void edge_agg(const ushort* __restrict__ Xbf, const int* __restrict__ adjAll,
                         const int* __restrict__ offC, const float* __restrict__ degE,
                         ushort* __restrict__ Ye) {
    int gid = blockIdx.x * blockDim.x + threadIdx.x;
    int edge = gid >> 6;
    int lane = gid & 63;
    if (edge >= N_EDGES) return;
    int half = lane >> 5;
    int col8 = (lane & 31) * 8;
    int b = offC[edge], e = offC[edge + 1];
    float a[8] = {0.f, 0.f, 0.f, 0.f, 0.f, 0.f, 0.f, 0.f};
    for (int i = b; i < e; i += 2) {
        int i2 = i + half;
        bool valid = i2 < e;
        int row = adjAll[valid ? i2 : i];
        ushortx8 x = *reinterpret_cast<const ushortx8*>(Xbf + (size_t)row * D + col8);
        if (valid) {
#pragma unroll
            for (int k = 0; k < 8; ++k) a[k] += bf2f(x[k]);
        }
    }
#pragma unroll
    for (int k = 0; k < 8; ++k) a[k] += __shfl_xor(a[k], 32, 64);
    int cnt = e - b;
    float s = degE[edge] / (float)(cnt > 1 ? cnt : 1);
    int k0 = half * 4;
    ushortx4 o;
    o[0] = f2bf(a[k0 + 0] * s); o[1] = f2bf(a[k0 + 1] * s);
    o[2] = f2bf(a[k0 + 2] * s); o[3] = f2bf(a[k0 + 3] * s);
    *reinterpret_cast<ushortx4*>(Ye + (size_t)edge * D + col8 + k0) = o;
}

// ---------------- phase 2: MFMA GEMM  Ze[MP,256] = Ye[MP,256] @ W  (bf16, LDS-free) ----------------

__global__ void __launch_bounds__(256) gemm_mfma(const ushort* __restrict__ A,
                                                 const ushort* __restrict__ WT,
                                                 ushort* __restrict__ C, int M) {
    int wid  = threadIdx.x >> 6;
    int lane = threadIdx.x & 63;
    int row0 = blockIdx.x * 64 + wid * 16;
    int lr  = lane & 15;
    int lk8 = (lane >> 4) * 8;
    f32x4 acc[16];
#pragma unroll
    for (int t = 0; t < 16; ++t) acc[t] = (f32x4){0.f, 0.f, 0.f, 0.f};
    int arow = row0 + lr;
    if (arow >= M) arow = M - 1;
    const ushort* aptr = A + (size_t)arow * D;
#pragma unroll
    for (int k0 = 0; k0 < D; k0 += 32) {
        short8 af = *reinterpret_cast<const short8*>(aptr + k0 + lk8);
#pragma unroll
        for (int t = 0; t < 16; ++t) {
            short8 bf = *reinterpret_cast<const short8*>(
                WT + (size_t)(t * 16 + lr) * D + k0 + lk8);
            acc[t] = __builtin_amdgcn_mfma_f32_16x16x32_bf16(af, bf, acc[t], 0, 0, 0);
        }
    }
    int crow = row0 + (lane >> 4) * 4;
#pragma unroll
    for (int t = 0; t < 16; ++t) {
        int ccol = t * 16 + lr;
#pragma unroll
        for (int r = 0; r < 4; ++r) {
            int rr = crow + r;
            if (rr < M) C[(size_t)rr * D + ccol] = f2bf(acc[t][r]);
        }
    }
}

// ---------------- phase 3: node aggregation (one wave per node, dual-row 16B/lane) ----------------

__global__ void node_agg(const ushort* __restrict__ Ze, const int* __restrict__ adjAll,
                         const int* __restrict__ offC, const float* __restrict__ degV,
                         const float* __restrict__ bias, float* __restrict__ out) {
    int gid = blockIdx.x * blockDim.x + threadIdx.x;
    int node = gid >> 6;
    int lane = gid & 63;
    if (node >= N_NODES) return;
    int half = lane >> 5;
    int col8 = (lane & 31) * 8;
    int b = offC[N_EDGES + node], e = offC[N_EDGES + node + 1];
    float a[8] = {0.f, 0.f, 0.f, 0.f, 0.f, 0.f, 0.f, 0.f};
    for (int i = b; i < e; i += 2) {
        int i2 = i + half;
        bool valid = i2 < e;
        int row = adjAll[valid ? i2 : i];
        ushortx8 z = *reinterpret_cast<const ushortx8*>(Ze + (size_t)row * D + col8);
        if (valid) {
#pragma unroll
            for (int k = 0; k < 8; ++k) a[k] += bf2f(z[k]);
        }
    }
#pragma unroll
    for (int k = 0; k < 8; ++k) a[k] += __shfl_xor(a[k], 32, 64);
    float dv = degV[node];
    int k0 = half * 4;
    int c = col8 + k0;
    float4 b4 = *reinterpret_cast<const float4*>(bias + c);
    float4 o = {a[k0 + 0] * dv + b4.x, a[k0 + 1] * dv + b4.y,
                a[k0 + 2] * dv + b4.z, a[k0 + 3] * dv + b4.w};
    *reinterpret_cast<float4*>(out + (size_t)node * D + c) = o;
}

// ---------------- launch ----------------

extern "C" void kernel_launch(void* const* d_in, const int* in_sizes, int n_in,
                              void* d_out, int out_size, void* d_ws, size_t ws_size,
                              hipStream_t stream) {
    const float* input  = (const float*)d_in[0];
    const int*   V      = (const int*)d_in[1];
    const int*   E      = (const int*)d_in[2];
    const float* degV   = (const float*)d_in[3];
    const float* degE   = (const float*)d_in[4];
    const float* weight = (const float*)d_in[5];
    const float* bias   = (const float*)d_in[6];
    float* out = (float*)d_out;

    int* cntC   = (int*)d_ws;                       // NTOT
    int* gcur   = cntC + NTOT;                      // 128 (98 used), memset with cntC
    int* offC   = gcur + 128;                       // NTOT+1
    int* bsum   = offC + (NTOT + 1);                // 128
    int* adjAll = bsum + 128;                       // 2*NNZ
    uintptr_t p = (uintptr_t)(adjAll + 2 * NNZ_);
    p = (p + 255) & ~(uintptr_t)255;
    ushort* Xbf = (ushort*)p;                       // N_NODES*D   (51.2 MB)
    ushort* Ye  = Xbf + (size_t)N_NODES * D;        // MP*D        (12.8 MB)
    ushort* Ze  = Ye + (size_t)MP * D;              // MP*D        (12.8 MB)
    ushort* WT  = Ze + (size_t)MP * D;              // 256*256     (128 KB)
    int2* pairs = (int2*)Ye;                        // 98*CAP*8B = 19.3MB, aliases Ye+Ze (dead until edge_agg)

    hipMemsetAsync(cntC, 0, (size_t)(NTOT + 128) * sizeof(int), stream);

    front_kernel<<<WB + CB, 256, 0, stream>>>(weight, WT, input, Xbf);

    scatter1<<<(NNZ_ / 16 + 255) / 256, 256, 0, stream>>>(V, E, gcur, pairs);
    count2<<<NB, 256, 0, stream>>>(pairs, gcur, cntC);
    scan_bsum<<<NBLK, 256, 0, stream>>>(cntC, bsum, NTOT);
    scan_boff<<<1, 128, 0, stream>>>(bsum, NBLK);
    scan_write<<<NBLK, 256, 0, stream>>>(cntC, bsum, offC, NTOT);
    fill3<<<NB, 256, 0, stream>>>(pairs, gcur, offC, adjAll);

    edge_agg<<<(N_EDGES * 64 + 255) / 256, 256, 0, stream>>>(Xbf, adjAll, offC, degE, Ye);

    gemm_mfma<<<MP / 64, 256, 0, stream>>>(Ye, WT, Ze, N_EDGES);

    node_agg<<<(N_NODES * 64 + 255) / 256, 256, 0, stream>>>(Ze, adjAll, offC, degV, bias, out);
}

// Round 9
// 262.827 us; speedup vs baseline: 3.4457x; 1.0387x over previous
//
#include <hip/hip_runtime.h>
#include <stdint.h>

#define N_NODES 100000
#define N_EDGES 25000
#define NNZ_    800000
#define D       256
#define NTOT    (N_EDGES + N_NODES)
#define SB      1024
#define NBLK    ((NTOT + SB) / SB)
#define MP      25024                 // N_EDGES padded to 64

// bucketed CSR build
#define SHE   9                       // edge keys per bucket = 512
#define SHV   11                      // node keys per bucket = 2048
#define WKE   512
#define WKV   2048
#define NBKE  ((N_EDGES + WKE - 1) / WKE)   // 49
#define NBKV  ((N_NODES + WKV - 1) / WKV)   // 49
#define NB    (NBKE + NBKV)                 // 98
#define CAP   24576                   // pairs capacity per bucket (mean 16384)

#define SC1B ((NNZ_ / 16 + 255) / 256)      // 196 scatter blocks (16 items/thread)
#define WB 256                              // cvt_wt blocks
#define CB ((N_NODES * D / 8 + 255) / 256)  // cvt_in blocks

typedef short  short8   __attribute__((ext_vector_type(8)));
typedef float  f32x4    __attribute__((ext_vector_type(4)));
typedef ushort ushortx8 __attribute__((ext_vector_type(8)));
typedef ushort ushortx4 __attribute__((ext_vector_type(4)));

__device__ __forceinline__ ushort f2bf(float f) {
    uint32_t u = __float_as_uint(f);
    uint32_t r = u + 0x7fffu + ((u >> 16) & 1u);
    return (ushort)(r >> 16);
}
__device__ __forceinline__ float bf2f(ushort u) {
    return __uint_as_float(((uint32_t)u) << 16);
}

// ---------------- fused front: scatter1 (critical path, first) + cvt_wt + cvt_in ----------------

__global__ void __launch_bounds__(256) front_kernel(const int* __restrict__ V,
                                                    const int* __restrict__ E,
                                                    int* __restrict__ gcur,
                                                    int2* __restrict__ pairs,
                                                    const float* __restrict__ W,
                                                    ushort* __restrict__ WT,
                                                    const float* __restrict__ in,
                                                    ushort* __restrict__ Xbf) {
    __shared__ int cnt[NB], base[NB], lcur[NB];
    int b = blockIdx.x, t = threadIdx.x;
    if (b < SC1B) {
        // ---- bucket scatter: block-local count, one reserve atomic, burst writes ----
        for (int j = t; j < NB; j += 256) cnt[j] = 0;
        __syncthreads();
        int i0 = (b * 256 + t) * 16;
        bool act = i0 < NNZ_;
        if (act) {
#pragma unroll
            for (int c = 0; c < 16; c += 4) {
                int4 e = *reinterpret_cast<const int4*>(E + i0 + c);
                int4 v = *reinterpret_cast<const int4*>(V + i0 + c);
                atomicAdd(&cnt[e.x >> SHE], 1);
                atomicAdd(&cnt[e.y >> SHE], 1);
                atomicAdd(&cnt[e.z >> SHE], 1);
                atomicAdd(&cnt[e.w >> SHE], 1);
                atomicAdd(&cnt[NBKE + (v.x >> SHV)], 1);
                atomicAdd(&cnt[NBKE + (v.y >> SHV)], 1);
                atomicAdd(&cnt[NBKE + (v.z >> SHV)], 1);
                atomicAdd(&cnt[NBKE + (v.w >> SHV)], 1);
            }
        }
        __syncthreads();
        for (int j = t; j < NB; j += 256) {
            int c = cnt[j];
            base[j] = c ? atomicAdd(&gcur[j], c) : 0;
            lcur[j] = 0;
        }
        __syncthreads();
        if (act) {
#pragma unroll
            for (int c = 0; c < 16; c += 4) {
                int4 e = *reinterpret_cast<const int4*>(E + i0 + c);
                int4 v = *reinterpret_cast<const int4*>(V + i0 + c);
                int ev[4] = {e.x, e.y, e.z, e.w};
                int vv[4] = {v.x, v.y, v.z, v.w};
#pragma unroll
                for (int k = 0; k < 4; ++k) {
                    int b1 = ev[k] >> SHE;
                    int p1 = base[b1] + atomicAdd(&lcur[b1], 1);
                    if (p1 < CAP) pairs[(size_t)b1 * CAP + p1] = make_int2(ev[k], vv[k]);
                    int b2 = NBKE + (vv[k] >> SHV);
                    int p2 = base[b2] + atomicAdd(&lcur[b2], 1);
                    if (p2 < CAP) pairs[(size_t)b2 * CAP + p2] = make_int2(vv[k], ev[k]);
                }
            }
        }
    } else if (b < SC1B + WB) {
        int g = (b - SC1B) * 256 + t;
        int n = g >> 8, k = g & 255;
        WT[(size_t)n * 256 + k] = f2bf(W[(size_t)k * 256 + n]);
    } else {
        int i = (b - SC1B - WB) * 256 + t;
        if (i >= N_NODES * D / 8) return;
        const f32x4* p = reinterpret_cast<const f32x4*>(in) + (size_t)i * 2;
        f32x4 a = __builtin_nontemporal_load(p);
        f32x4 c = __builtin_nontemporal_load(p + 1);
        ushortx8 o;
        o[0] = f2bf(a[0]); o[1] = f2bf(a[1]); o[2] = f2bf(a[2]); o[3] = f2bf(a[3]);
        o[4] = f2bf(c[0]); o[5] = f2bf(c[1]); o[6] = f2bf(c[2]); o[7] = f2bf(c[3]);
        *(reinterpret_cast<ushortx8*>(Xbf) + i) = o;
    }
}

// ---------------- pass 2: per-bucket LDS histogram -> coalesced counts ----------------

__global__ void __launch_bounds__(256) count2(const int2* __restrict__ pairs,
                                              const int* __restrict__ gcur,
                                              int* __restrict__ cntC) {
    __shared__ int hist[WKV];
    int b = blockIdx.x, t = threadIdx.x;
    bool eside = b < NBKE;
    int kb    = eside ? b * WKE : (b - NBKE) * WKV;
    int wk    = eside ? WKE : WKV;
    int nk    = eside ? min(WKE, N_EDGES - kb) : min(WKV, N_NODES - kb);
    int obase = eside ? kb : N_EDGES + kb;
    for (int j = t; j < wk; j += 256) hist[j] = 0;
    __syncthreads();
    int n = min(gcur[b], CAP);
    const int2* p = pairs + (size_t)b * CAP;
    for (int i = t; i < n; i += 256) {
        int2 pr = p[i];
        atomicAdd(&hist[pr.x - kb], 1);
    }
    __syncthreads();
    for (int j = t; j < nk; j += 256) cntC[obase + j] = hist[j];
}

// ---------------- hierarchical scan ----------------

__global__ void __launch_bounds__(256) scan_bsum(const int* __restrict__ in,
                                                 int* __restrict__ bsum, int n) {
    __shared__ int sh[256];
    int b = blockIdx.x, t = threadIdx.x;
    int base = b * SB + t * 4;
    int s = 0;
    if (base + 4 <= n) {
        int4 v = *reinterpret_cast<const int4*>(in + base);
        s = v.x + v.y + v.z + v.w;
    } else {
        for (int k = 0; k < 4; ++k)
            if (base + k < n) s += in[base + k];
    }
    sh[t] = s;
    __syncthreads();
    for (int off = 128; off > 0; off >>= 1) {
        if (t < off) sh[t] += sh[t + off];
        __syncthreads();
    }
    if (t == 0) bsum[b] = sh[0];
}

__global__ void __launch_bounds__(128) scan_boff(int* __restrict__ bsum, int nb) {
    __shared__ int sh[128];
    int t = threadIdx.x;
    int v = (t < nb) ? bsum[t] : 0;
    sh[t] = v;
    __syncthreads();
    for (int off = 1; off < 128; off <<= 1) {
        int u = (t >= off) ? sh[t - off] : 0;
        __syncthreads();
        sh[t] += u;
        __syncthreads();
    }
    if (t < nb) bsum[t] = sh[t] - v;
}

__global__ void __launch_bounds__(256) scan_write(const int* __restrict__ in,
                                                  const int* __restrict__ bsum,
                                                  int* __restrict__ off, int n) {
    __shared__ int sh[256];
    int b = blockIdx.x, t = threadIdx.x;
    int base = b * SB + t * 4;
    int v0 = 0, v1 = 0, v2 = 0, v3 = 0;
    if (base + 4 <= n) {
        int4 v = *reinterpret_cast<const int4*>(in + base);
        v0 = v.x; v1 = v.y; v2 = v.z; v3 = v.w;
    } else {
        if (base + 0 < n) v0 = in[base + 0];
        if (base + 1 < n) v1 = in[base + 1];
        if (base + 2 < n) v2 = in[base + 2];
        if (base + 3 < n) v3 = in[base + 3];
    }
    int s = v0 + v1 + v2 + v3;
    sh[t] = s;
    __syncthreads();
    for (int o = 1; o < 256; o <<= 1) {
        int u = (t >= o) ? sh[t - o] : 0;
        __syncthreads();
        sh[t] += u;
        __syncthreads();
    }
    int excl = bsum[b] + sh[t] - s;
    if (base + 0 <= n) off[base + 0] = excl; excl += v0;
    if (base + 1 <= n) off[base + 1] = excl; excl += v1;
    if (base + 2 <= n) off[base + 2] = excl; excl += v2;
    if (base + 3 <= n) off[base + 3] = excl;
}

// ---------------- pass 3: per-bucket fill (LDS cursors, windowed writes) ----------------

__global__ void __launch_bounds__(256) fill3(const int2* __restrict__ pairs,
                                             const int* __restrict__ gcur,
                                             const int* __restrict__ offC,
                                             int* __restrict__ adjAll) {
    __shared__ int cur[WKV];
    int b = blockIdx.x, t = threadIdx.x;
    bool eside = b < NBKE;
    int kb    = eside ? b * WKE : (b - NBKE) * WKV;
    int nk    = eside ? min(WKE, N_EDGES - kb) : min(WKV, N_NODES - kb);
    int obase = eside ? kb : N_EDGES + kb;
    for (int j = t; j < nk; j += 256) cur[j] = offC[obase + j];
    __syncthreads();
    int n = min(gcur[b], CAP);
    const int2* p = pairs + (size_t)b * CAP;
    for (int i = t; i < n; i += 256) {
        int2 pr = p[i];
        int slot = atomicAdd(&cur[pr.x - kb], 1);
        adjAll[slot] = pr.y;
    }
}

// ---------------- phase 1: edge aggregation (one wave per edge, 4-row unrolled) ----------------

__global__ void edge_agg(const ushort* __restrict__ Xbf, const int* __restrict__ adjAll,
                         const int* __restrict__ offC, const float* __restrict__ degE,
                         ushort* __restrict__ Ye) {
    int gid = blockIdx.x * blockDim.x + threadIdx.x;
    int edge = gid >> 6;
    int lane = gid & 63;
    if (edge >= N_EDGES) return;
    int half = lane >> 5;
    int col8 = (lane & 31) * 8;
    int b = offC[edge], e = offC[edge + 1];
    float a[8] = {0.f, 0.f, 0.f, 0.f, 0.f, 0.f, 0.f, 0.f};
    for (int i = b; i < e; i += 4) {
        int ia = i + half, ib = i + 2 + half;
        bool va = ia < e, vb = ib < e;
        int ra = adjAll[va ? ia : b];
        int rb = adjAll[vb ? ib : b];
        ushortx8 xa = *reinterpret_cast<const ushortx8*>(Xbf + (size_t)ra * D + col8);
        ushortx8 xb = *reinterpret_cast<const ushortx8*>(Xbf + (size_t)rb * D + col8);
        if (va) {
#pragma unroll
            for (int k = 0; k < 8; ++k) a[k] += bf2f(xa[k]);
        }
        if (vb) {
#pragma unroll
            for (int k = 0; k < 8; ++k) a[k] += bf2f(xb[k]);
        }
    }
#pragma unroll
    for (int k = 0; k < 8; ++k) a[k] += __shfl_xor(a[k], 32, 64);
    int cnt = e - b;
    float s = degE[edge] / (float)(cnt > 1 ? cnt : 1);
    int k0 = half * 4;
    ushortx4 o;
    o[0] = f2bf(a[k0 + 0] * s); o[1] = f2bf(a[k0 + 1] * s);
    o[2] = f2bf(a[k0 + 2] * s); o[3] = f2bf(a[k0 + 3] * s);
    *reinterpret_cast<ushortx4*>(Ye + (size_t)edge * D + col8 + k0) = o;
}

// ---------------- phase 2: MFMA GEMM  Ze[MP,256] = Ye[MP,256] @ W  (bf16, LDS-free) ----------------

__global__ void __launch_bounds__(256) gemm_mfma(const ushort* __restrict__ A,
                                                 const ushort* __restrict__ WT,
                                                 ushort* __restrict__ C, int M) {
    int wid  = threadIdx.x >> 6;
    int lane = threadIdx.x & 63;
    int row0 = blockIdx.x * 64 + wid * 16;
    int lr  = lane & 15;
    int lk8 = (lane >> 4) * 8;
    f32x4 acc[16];
#pragma unroll
    for (int t = 0; t < 16; ++t) acc[t] = (f32x4){0.f, 0.f, 0.f, 0.f};
    int arow = row0 + lr;
    if (arow >= M) arow = M - 1;
    const ushort* aptr = A + (size_t)arow * D;
#pragma unroll
    for (int k0 = 0; k0 < D; k0 += 32) {
        short8 af = *reinterpret_cast<const short8*>(aptr + k0 + lk8);
#pragma unroll
        for (int t = 0; t < 16; ++t) {
            short8 bf = *reinterpret_cast<const short8*>(
                WT + (size_t)(t * 16 + lr) * D + k0 + lk8);
            acc[t] = __builtin_amdgcn_mfma_f32_16x16x32_bf16(af, bf, acc[t], 0, 0, 0);
        }
    }
    int crow = row0 + (lane >> 4) * 4;
#pragma unroll
    for (int t = 0; t < 16; ++t) {
        int ccol = t * 16 + lr;
#pragma unroll
        for (int r = 0; r < 4; ++r) {
            int rr = crow + r;
            if (rr < M) C[(size_t)rr * D + ccol] = f2bf(acc[t][r]);
        }
    }
}

// ---------------- phase 3: node aggregation (one wave per node, 4-row unrolled, NT store) ----------------

__global__ void node_agg(const ushort* __restrict__ Ze, const int* __restrict__ adjAll,
                         const int* __restrict__ offC, const float* __restrict__ degV,
                         const float* __restrict__ bias, float* __restrict__ out) {
    int gid = blockIdx.x * blockDim.x + threadIdx.x;
    int node = gid >> 6;
    int lane = gid & 63;
    if (node >= N_NODES) return;
    int half = lane >> 5;
    int col8 = (lane & 31) * 8;
    int b = offC[N_EDGES + node], e = offC[N_EDGES + node + 1];
    float a[8] = {0.f, 0.f, 0.f, 0.f, 0.f, 0.f, 0.f, 0.f};
    for (int i = b; i < e; i += 4) {
        int ia = i + half, ib = i + 2 + half;
        bool va = ia < e, vb = ib < e;
        int ra = adjAll[va ? ia : b];
        int rb = adjAll[vb ? ib : b];
        ushortx8 za = *reinterpret_cast<const ushortx8*>(Ze + (size_t)ra * D + col8);
        ushortx8 zb = *reinterpret_cast<const ushortx8*>(Ze + (size_t)rb * D + col8);
        if (va) {
#pragma unroll
            for (int k = 0; k < 8; ++k) a[k] += bf2f(za[k]);
        }
        if (vb) {
#pragma unroll
            for (int k = 0; k < 8; ++k) a[k] += bf2f(zb[k]);
        }
    }
#pragma unroll
    for (int k = 0; k < 8; ++k) a[k] += __shfl_xor(a[k], 32, 64);
    float dv = degV[node];
    int k0 = half * 4;
    int c = col8 + k0;
    const f32x4* bp = reinterpret_cast<const f32x4*>(bias + c);
    f32x4 b4 = *bp;
    f32x4 o;
    o[0] = a[k0 + 0] * dv + b4[0];
    o[1] = a[k0 + 1] * dv + b4[1];
    o[2] = a[k0 + 2] * dv + b4[2];
    o[3] = a[k0 + 3] * dv + b4[3];
    __builtin_nontemporal_store(o, reinterpret_cast<f32x4*>(out + (size_t)node * D + c));
}

// ---------------- launch ----------------

extern "C" void kernel_launch(void* const* d_in, const int* in_sizes, int n_in,
                              void* d_out, int out_size, void* d_ws, size_t ws_size,
                              hipStream_t stream) {
    const float* input  = (const float*)d_in[0];
    const int*   V      = (const int*)d_in[1];
    const int*   E      = (const int*)d_in[2];
    const float* degV   = (const float*)d_in[3];
    const float* degE   = (const float*)d_in[4];
    const float* weight = (const float*)d_in[5];
    const float* bias   = (const float*)d_in[6];
    float* out = (float*)d_out;

    int* cntC   = (int*)d_ws;                       // NTOT
    int* gcur   = cntC + NTOT;                      // 128 (98 used), memset with cntC
    int* offC   = gcur + 128;                       // NTOT+1
    int* bsum   = offC + (NTOT + 1);                // 128
    int* adjAll = bsum + 128;                       // 2*NNZ
    uintptr_t p = (uintptr_t)(adjAll + 2 * NNZ_);
    p = (p + 255) & ~(uintptr_t)255;
    ushort* Xbf = (ushort*)p;                       // N_NODES*D   (51.2 MB)
    ushort* Ye  = Xbf + (size_t)N_NODES * D;        // MP*D        (12.8 MB)
    ushort* Ze  = Ye + (size_t)MP * D;              // MP*D        (12.8 MB)
    ushort* WT  = Ze + (size_t)MP * D;              // 256*256     (128 KB)
    int2* pairs = (int2*)Ye;                        // 19.3MB, aliases Ye+Ze (dead until edge_agg)

    hipMemsetAsync(cntC, 0, (size_t)(NTOT + 128) * sizeof(int), stream);

    front_kernel<<<SC1B + WB + CB, 256, 0, stream>>>(V, E, gcur, pairs,
                                                     weight, WT, input, Xbf);

    count2<<<NB, 256, 0, stream>>>(pairs, gcur, cntC);
    scan_bsum<<<NBLK, 256, 0, stream>>>(cntC, bsum, NTOT);
    scan_boff<<<1, 128, 0, stream>>>(bsum, NBLK);
    scan_write<<<NBLK, 256, 0, stream>>>(cntC, bsum, offC, NTOT);
    fill3<<<NB, 256, 0, stream>>>(pairs, gcur, offC, adjAll);

    edge_agg<<<(N_EDGES * 64 + 255) / 256, 256, 0, stream>>>(Xbf, adjAll, offC, degE, Ye);

    gemm_mfma<<<MP / 64, 256, 0, stream>>>(Ye, WT, Ze, N_EDGES);

    node_agg<<<(N_NODES * 64 + 255) / 256, 256, 0, stream>>>(Ze, adjAll, offC, degV, bias, out);
}

// Round 10
// 251.311 us; speedup vs baseline: 3.6036x; 1.0458x over previous
//
#include <hip/hip_runtime.h>
#include <stdint.h>

#define N_NODES 100000
#define N_EDGES 25000
#define NNZ_    800000
#define D       256
#define NTOT    (N_EDGES + N_NODES)
#define SB      1024
#define NBLK    ((NTOT + SB) / SB)
#define MP      25024                 // N_EDGES padded to 64

// bucketed CSR build
#define SHE   9                       // edge keys per bucket = 512
#define SHV   11                      // node keys per bucket = 2048
#define WKE   512
#define WKV   2048
#define NBKE  ((N_EDGES + WKE - 1) / WKE)   // 49
#define NBKV  ((N_NODES + WKV - 1) / WKV)   // 49
#define NB    (NBKE + NBKV)                 // 98
#define CAP   24576                   // pairs capacity per bucket (mean 16384)

#define SC1B ((NNZ_ / 16 + 255) / 256)      // 196 scatter blocks (16 items/thread)
#define WB 256                              // cvt_wt blocks
#define CB ((N_NODES * D / 8 + 255) / 256)  // cvt_in blocks

typedef short  short8   __attribute__((ext_vector_type(8)));
typedef float  f32x4    __attribute__((ext_vector_type(4)));
typedef ushort ushortx8 __attribute__((ext_vector_type(8)));
typedef ushort ushortx4 __attribute__((ext_vector_type(4)));

__device__ __forceinline__ ushort f2bf(float f) {
    uint32_t u = __float_as_uint(f);
    uint32_t r = u + 0x7fffu + ((u >> 16) & 1u);
    return (ushort)(r >> 16);
}
__device__ __forceinline__ float bf2f(ushort u) {
    return __uint_as_float(((uint32_t)u) << 16);
}

// ---------------- fused front: scatter1 (critical path, first) + cvt_wt + cvt_in ----------------

__global__ void __launch_bounds__(256) front_kernel(const int* __restrict__ V,
                                                    const int* __restrict__ E,
                                                    int* __restrict__ gcur,
                                                    int2* __restrict__ pairs,
                                                    const float* __restrict__ W,
                                                    ushort* __restrict__ WT,
                                                    const float* __restrict__ in,
                                                    ushort* __restrict__ Xbf) {
    __shared__ int cnt[NB], base[NB], lcur[NB];
    int b = blockIdx.x, t = threadIdx.x;
    if (b < SC1B) {
        for (int j = t; j < NB; j += 256) cnt[j] = 0;
        __syncthreads();
        int i0 = (b * 256 + t) * 16;
        bool act = i0 < NNZ_;
        if (act) {
#pragma unroll
            for (int c = 0; c < 16; c += 4) {
                int4 e = *reinterpret_cast<const int4*>(E + i0 + c);
                int4 v = *reinterpret_cast<const int4*>(V + i0 + c);
                atomicAdd(&cnt[e.x >> SHE], 1);
                atomicAdd(&cnt[e.y >> SHE], 1);
                atomicAdd(&cnt[e.z >> SHE], 1);
                atomicAdd(&cnt[e.w >> SHE], 1);
                atomicAdd(&cnt[NBKE + (v.x >> SHV)], 1);
                atomicAdd(&cnt[NBKE + (v.y >> SHV)], 1);
                atomicAdd(&cnt[NBKE + (v.z >> SHV)], 1);
                atomicAdd(&cnt[NBKE + (v.w >> SHV)], 1);
            }
        }
        __syncthreads();
        for (int j = t; j < NB; j += 256) {
            int c = cnt[j];
            base[j] = c ? atomicAdd(&gcur[j], c) : 0;
            lcur[j] = 0;
        }
        __syncthreads();
        if (act) {
#pragma unroll
            for (int c = 0; c < 16; c += 4) {
                int4 e = *reinterpret_cast<const int4*>(E + i0 + c);
                int4 v = *reinterpret_cast<const int4*>(V + i0 + c);
                int ev[4] = {e.x, e.y, e.z, e.w};
                int vv[4] = {v.x, v.y, v.z, v.w};
#pragma unroll
                for (int k = 0; k < 4; ++k) {
                    int b1 = ev[k] >> SHE;
                    int p1 = base[b1] + atomicAdd(&lcur[b1], 1);
                    if (p1 < CAP) pairs[(size_t)b1 * CAP + p1] = make_int2(ev[k], vv[k]);
                    int b2 = NBKE + (vv[k] >> SHV);
                    int p2 = base[b2] + atomicAdd(&lcur[b2], 1);
                    if (p2 < CAP) pairs[(size_t)b2 * CAP + p2] = make_int2(vv[k], ev[k]);
                }
            }
        }
    } else if (b < SC1B + WB) {
        int g = (b - SC1B) * 256 + t;
        int n = g >> 8, k = g & 255;
        WT[(size_t)n * 256 + k] = f2bf(W[(size_t)k * 256 + n]);
    } else {
        int i = (b - SC1B - WB) * 256 + t;
        if (i >= N_NODES * D / 8) return;
        const f32x4* p = reinterpret_cast<const f32x4*>(in) + (size_t)i * 2;
        f32x4 a = __builtin_nontemporal_load(p);
        f32x4 c = __builtin_nontemporal_load(p + 1);
        ushortx8 o;
        o[0] = f2bf(a[0]); o[1] = f2bf(a[1]); o[2] = f2bf(a[2]); o[3] = f2bf(a[3]);
        o[4] = f2bf(c[0]); o[5] = f2bf(c[1]); o[6] = f2bf(c[2]); o[7] = f2bf(c[3]);
        *(reinterpret_cast<ushortx8*>(Xbf) + i) = o;
    }
}

// ---------------- pass 2: per-bucket LDS histogram -> coalesced counts ----------------

__global__ void __launch_bounds__(256) count2(const int2* __restrict__ pairs,
                                              const int* __restrict__ gcur,
                                              int* __restrict__ cntC) {
    __shared__ int hist[WKV];
    int b = blockIdx.x, t = threadIdx.x;
    bool eside = b < NBKE;
    int kb    = eside ? b * WKE : (b - NBKE) * WKV;
    int wk    = eside ? WKE : WKV;
    int nk    = eside ? min(WKE, N_EDGES - kb) : min(WKV, N_NODES - kb);
    int obase = eside ? kb : N_EDGES + kb;
    for (int j = t; j < wk; j += 256) hist[j] = 0;
    __syncthreads();
    int n = min(gcur[b], CAP);
    const int2* p = pairs + (size_t)b * CAP;
    for (int i = t; i < n; i += 256) {
        int2 pr = p[i];
        atomicAdd(&hist[pr.x - kb], 1);
    }
    __syncthreads();
    for (int j = t; j < nk; j += 256) cntC[obase + j] = hist[j];
}

// ---------------- hierarchical scan ----------------

__global__ void __launch_bounds__(256) scan_bsum(const int* __restrict__ in,
                                                 int* __restrict__ bsum, int n) {
    __shared__ int sh[256];
    int b = blockIdx.x, t = threadIdx.x;
    int base = b * SB + t * 4;
    int s = 0;
    if (base + 4 <= n) {
        int4 v = *reinterpret_cast<const int4*>(in + base);
        s = v.x + v.y + v.z + v.w;
    } else {
        for (int k = 0; k < 4; ++k)
            if (base + k < n) s += in[base + k];
    }
    sh[t] = s;
    __syncthreads();
    for (int off = 128; off > 0; off >>= 1) {
        if (t < off) sh[t] += sh[t + off];
        __syncthreads();
    }
    if (t == 0) bsum[b] = sh[0];
}

__global__ void __launch_bounds__(128) scan_boff(int* __restrict__ bsum, int nb) {
    __shared__ int sh[128];
    int t = threadIdx.x;
    int v = (t < nb) ? bsum[t] : 0;
    sh[t] = v;
    __syncthreads();
    for (int off = 1; off < 128; off <<= 1) {
        int u = (t >= off) ? sh[t - off] : 0;
        __syncthreads();
        sh[t] += u;
        __syncthreads();
    }
    if (t < nb) bsum[t] = sh[t] - v;
}

__global__ void __launch_bounds__(256) scan_write(const int* __restrict__ in,
                                                  const int* __restrict__ bsum,
                                                  int* __restrict__ off, int n) {
    __shared__ int sh[256];
    int b = blockIdx.x, t = threadIdx.x;
    int base = b * SB + t * 4;
    int v0 = 0, v1 = 0, v2 = 0, v3 = 0;
    if (base + 4 <= n) {
        int4 v = *reinterpret_cast<const int4*>(in + base);
        v0 = v.x; v1 = v.y; v2 = v.z; v3 = v.w;
    } else {
        if (base + 0 < n) v0 = in[base + 0];
        if (base + 1 < n) v1 = in[base + 1];
        if (base + 2 < n) v2 = in[base + 2];
        if (base + 3 < n) v3 = in[base + 3];
    }
    int s = v0 + v1 + v2 + v3;
    sh[t] = s;
    __syncthreads();
    for (int o = 1; o < 256; o <<= 1) {
        int u = (t >= o) ? sh[t - o] : 0;
        __syncthreads();
        sh[t] += u;
        __syncthreads();
    }
    int excl = bsum[b] + sh[t] - s;
    if (base + 0 <= n) off[base + 0] = excl; excl += v0;
    if (base + 1 <= n) off[base + 1] = excl; excl += v1;
    if (base + 2 <= n) off[base + 2] = excl; excl += v2;
    if (base + 3 <= n) off[base + 3] = excl;
}

// ---------------- pass 3: per-bucket fill (LDS cursors, windowed writes) ----------------

__global__ void __launch_bounds__(256) fill3(const int2* __restrict__ pairs,
                                             const int* __restrict__ gcur,
                                             const int* __restrict__ offC,
                                             int* __restrict__ adjAll) {
    __shared__ int cur[WKV];
    int b = blockIdx.x, t = threadIdx.x;
    bool eside = b < NBKE;
    int kb    = eside ? b * WKE : (b - NBKE) * WKV;
    int nk    = eside ? min(WKE, N_EDGES - kb) : min(WKV, N_NODES - kb);
    int obase = eside ? kb : N_EDGES + kb;
    for (int j = t; j < nk; j += 256) cur[j] = offC[obase + j];
    __syncthreads();
    int n = min(gcur[b], CAP);
    const int2* p = pairs + (size_t)b * CAP;
    for (int i = t; i < n; i += 256) {
        int2 pr = p[i];
        int slot = atomicAdd(&cur[pr.x - kb], 1);
        adjAll[slot] = pr.y;
    }
}

// ---------------- shared gather core: lane-parallel index prefetch + shuffle broadcast ----------------
// Accumulates sum over rows adjAll[b..e) of src[row][col8..col8+8) into a[0..8).
// half 0 takes even local rows, half 1 odd; merge with shfl_xor(32) after.

__device__ __forceinline__ void gather_rows(const ushort* __restrict__ src,
                                            const int* __restrict__ adjAll,
                                            int b, int cnt, int half, int col8,
                                            float a[8], int lane) {
    for (int c0 = 0; c0 < cnt; c0 += 64) {
        int rem = cnt - c0;                        // > 0
        int li = c0 + min(lane, rem - 1);
        int myidx = adjAll[b + li];                // one coalesced load per chunk
        int lim = min(rem, 64);
        for (int j0 = 0; j0 < lim; j0 += 8) {
            int r0 = __shfl(myidx, j0 + 0 + half, 64);
            int r1 = __shfl(myidx, j0 + 2 + half, 64);
            int r2 = __shfl(myidx, j0 + 4 + half, 64);
            int r3 = __shfl(myidx, j0 + 6 + half, 64);
            // issue all 4 loads before any use (independent; clamped idx -> safe addr)
            ushortx8 x0 = *reinterpret_cast<const ushortx8*>(src + (size_t)r0 * D + col8);
            ushortx8 x1 = *reinterpret_cast<const ushortx8*>(src + (size_t)r1 * D + col8);
            ushortx8 x2 = *reinterpret_cast<const ushortx8*>(src + (size_t)r2 * D + col8);
            ushortx8 x3 = *reinterpret_cast<const ushortx8*>(src + (size_t)r3 * D + col8);
            if (j0 + 0 + half < lim) {
#pragma unroll
                for (int k = 0; k < 8; ++k) a[k] += bf2f(x0[k]);
            }
            if (j0 + 2 + half < lim) {
#pragma unroll
                for (int k = 0; k < 8; ++k) a[k] += bf2f(x1[k]);
            }
            if (j0 + 4 + half < lim) {
#pragma unroll
                for (int k = 0; k < 8; ++k) a[k] += bf2f(x2[k]);
            }
            if (j0 + 6 + half < lim) {
#pragma unroll
                for (int k = 0; k < 8; ++k) a[k] += bf2f(x3[k]);
            }
        }
    }
}

// ---------------- phase 1: edge aggregation (one wave per edge) ----------------

__global__ void edge_agg(const ushort* __restrict__ Xbf, const int* __restrict__ adjAll,
                         const int* __restrict__ offC, const float* __restrict__ degE,
                         ushort* __restrict__ Ye) {
    int gid = blockIdx.x * blockDim.x + threadIdx.x;
    int edge = gid >> 6;
    int lane = gid & 63;
    if (edge >= N_EDGES) return;
    int half = lane >> 5;
    int col8 = (lane & 31) * 8;
    int b = offC[edge], e = offC[edge + 1];
    int cnt = e - b;
    float a[8] = {0.f, 0.f, 0.f, 0.f, 0.f, 0.f, 0.f, 0.f};
    gather_rows(Xbf, adjAll, b, cnt, half, col8, a, lane);
#pragma unroll
    for (int k = 0; k < 8; ++k) a[k] += __shfl_xor(a[k], 32, 64);
    float s = degE[edge] / (float)(cnt > 1 ? cnt : 1);
    int k0 = half * 4;
    ushortx4 o;
    o[0] = f2bf(a[k0 + 0] * s); o[1] = f2bf(a[k0 + 1] * s);
    o[2] = f2bf(a[k0 + 2] * s); o[3] = f2bf(a[k0 + 3] * s);
    *reinterpret_cast<ushortx4*>(Ye + (size_t)edge * D + col8 + k0) = o;
}

// ---------------- phase 2: MFMA GEMM  Ze[MP,256] = Ye[MP,256] @ W  (bf16, LDS-free) ----------------

__global__ void __launch_bounds__(256) gemm_mfma(const ushort* __restrict__ A,
                                                 const ushort* __restrict__ WT,
                                                 ushort* __restrict__ C, int M) {
    int wid  = threadIdx.x >> 6;
    int lane = threadIdx.x & 63;
    int row0 = blockIdx.x * 64 + wid * 16;
    int lr  = lane & 15;
    int lk8 = (lane >> 4) * 8;
    f32x4 acc[16];
#pragma unroll
    for (int t = 0; t < 16; ++t) acc[t] = (f32x4){0.f, 0.f, 0.f, 0.f};
    int arow = row0 + lr;
    if (arow >= M) arow = M - 1;
    const ushort* aptr = A + (size_t)arow * D;
#pragma unroll
    for (int k0 = 0; k0 < D; k0 += 32) {
        short8 af = *reinterpret_cast<const short8*>(aptr + k0 + lk8);
#pragma unroll
        for (int t = 0; t < 16; ++t) {
            short8 bf = *reinterpret_cast<const short8*>(
                WT + (size_t)(t * 16 + lr) * D + k0 + lk8);
            acc[t] = __builtin_amdgcn_mfma_f32_16x16x32_bf16(af, bf, acc[t], 0, 0, 0);
        }
    }
    int crow = row0 + (lane >> 4) * 4;
#pragma unroll
    for (int t = 0; t < 16; ++t) {
        int ccol = t * 16 + lr;
#pragma unroll
        for (int r = 0; r < 4; ++r) {
            int rr = crow + r;
            if (rr < M) C[(size_t)rr * D + ccol] = f2bf(acc[t][r]);
        }
    }
}

// ---------------- phase 3: node aggregation (one wave per node, NT store) ----------------

__global__ void node_agg(const ushort* __restrict__ Ze, const int* __restrict__ adjAll,
                         const int* __restrict__ offC, const float* __restrict__ degV,
                         const float* __restrict__ bias, float* __restrict__ out) {
    int gid = blockIdx.x * blockDim.x + threadIdx.x;
    int node = gid >> 6;
    int lane = gid & 63;
    if (node >= N_NODES) return;
    int half = lane >> 5;
    int col8 = (lane & 31) * 8;
    int b = offC[N_EDGES + node], e = offC[N_EDGES + node + 1];
    int cnt = e - b;
    float a[8] = {0.f, 0.f, 0.f, 0.f, 0.f, 0.f, 0.f, 0.f};
    gather_rows(Ze, adjAll, b, cnt, half, col8, a, lane);
#pragma unroll
    for (int k = 0; k < 8; ++k) a[k] += __shfl_xor(a[k], 32, 64);
    float dv = degV[node];
    int k0 = half * 4;
    int c = col8 + k0;
    f32x4 b4 = *reinterpret_cast<const f32x4*>(bias + c);
    f32x4 o;
    o[0] = a[k0 + 0] * dv + b4[0];
    o[1] = a[k0 + 1] * dv + b4[1];
    o[2] = a[k0 + 2] * dv + b4[2];
    o[3] = a[k0 + 3] * dv + b4[3];
    __builtin_nontemporal_store(o, reinterpret_cast<f32x4*>(out + (size_t)node * D + c));
}

// ---------------- launch ----------------

extern "C" void kernel_launch(void* const* d_in, const int* in_sizes, int n_in,
                              void* d_out, int out_size, void* d_ws, size_t ws_size,
                              hipStream_t stream) {
    const float* input  = (const float*)d_in[0];
    const int*   V      = (const int*)d_in[1];
    const int*   E      = (const int*)d_in[2];
    const float* degV   = (const float*)d_in[3];
    const float* degE   = (const float*)d_in[4];
    const float* weight = (const float*)d_in[5];
    const float* bias   = (const float*)d_in[6];
    float* out = (float*)d_out;

    int* cntC   = (int*)d_ws;                       // NTOT
    int* gcur   = cntC + NTOT;                      // 128 (98 used), memset with cntC
    int* offC   = gcur + 128;                       // NTOT+1
    int* bsum   = offC + (NTOT + 1);                // 128
    int* adjAll = bsum + 128;                       // 2*NNZ
    uintptr_t p = (uintptr_t)(adjAll + 2 * NNZ_);
    p = (p + 255) & ~(uintptr_t)255;
    ushort* Xbf = (ushort*)p;                       // N_NODES*D   (51.2 MB)
    ushort* Ye  = Xbf + (size_t)N_NODES * D;        // MP*D        (12.8 MB)
    ushort* Ze  = Ye + (size_t)MP * D;              // MP*D        (12.8 MB)
    ushort* WT  = Ze + (size_t)MP * D;              // 256*256     (128 KB)
    int2* pairs = (int2*)Ye;                        // 19.3MB, aliases Ye+Ze (dead until edge_agg)

    hipMemsetAsync(cntC, 0, (size_t)(NTOT + 128) * sizeof(int), stream);

    front_kernel<<<SC1B + WB + CB, 256, 0, stream>>>(V, E, gcur, pairs,
                                                     weight, WT, input, Xbf);

    count2<<<NB, 256, 0, stream>>>(pairs, gcur, cntC);
    scan_bsum<<<NBLK, 256, 0, stream>>>(cntC, bsum, NTOT);
    scan_boff<<<1, 128, 0, stream>>>(bsum, NBLK);
    scan_write<<<NBLK, 256, 0, stream>>>(cntC, bsum, offC, NTOT);
    fill3<<<NB, 256, 0, stream>>>(pairs, gcur, offC, adjAll);

    edge_agg<<<(N_EDGES * 64 + 255) / 256, 256, 0, stream>>>(Xbf, adjAll, offC, degE, Ye);

    gemm_mfma<<<MP / 64, 256, 0, stream>>>(Ye, WT, Ze, N_EDGES);

    node_agg<<<(N_NODES * 64 + 255) / 256, 256, 0, stream>>>(Ze, adjAll, offC, degV, bias, out);
}

// Round 11
// 241.051 us; speedup vs baseline: 3.7570x; 1.0426x over previous
//
#include <hip/hip_runtime.h>
#include <stdint.h>

#define N_NODES 100000
#define N_EDGES 25000
#define NNZ_    800000
#define D       256
#define NTOT    (N_EDGES + N_NODES)
#define MP      25024                 // N_EDGES padded to 64

// bucketed CSR build
#define SHE   9                       // edge keys per bucket = 512
#define SHV   11                      // node keys per bucket = 2048
#define WKE   512
#define WKV   2048
#define NBKE  ((N_EDGES + WKE - 1) / WKE)   // 49
#define NBKV  ((N_NODES + WKV - 1) / WKV)   // 49
#define NB    (NBKE + NBKV)                 // 98
#define CAP   24576                   // pairs capacity per bucket (mean 16384)

#define SC1B ((NNZ_ / 16 + 255) / 256)      // 196 scatter blocks (16 items/thread)
#define WB 256                              // cvt_wt blocks
#define CB ((N_NODES * D / 8 + 255) / 256)  // cvt_in blocks

typedef short  short8   __attribute__((ext_vector_type(8)));
typedef float  f32x4    __attribute__((ext_vector_type(4)));
typedef ushort ushortx8 __attribute__((ext_vector_type(8)));
typedef ushort ushortx4 __attribute__((ext_vector_type(4)));

__device__ __forceinline__ ushort f2bf(float f) {
    uint32_t u = __float_as_uint(f);
    uint32_t r = u + 0x7fffu + ((u >> 16) & 1u);
    return (ushort)(r >> 16);
}
__device__ __forceinline__ float bf2f(ushort u) {
    return __uint_as_float(((uint32_t)u) << 16);
}

// ---------------- fused front: scatter1 (critical path, first) + cvt_wt + cvt_in ----------------

__global__ void __launch_bounds__(256) front_kernel(const int* __restrict__ V,
                                                    const int* __restrict__ E,
                                                    int* __restrict__ gcur,
                                                    int2* __restrict__ pairs,
                                                    const float* __restrict__ W,
                                                    ushort* __restrict__ WT,
                                                    const float* __restrict__ in,
                                                    ushort* __restrict__ Xbf) {
    __shared__ int cnt[NB], base[NB], lcur[NB];
    int b = blockIdx.x, t = threadIdx.x;
    if (b < SC1B) {
        for (int j = t; j < NB; j += 256) cnt[j] = 0;
        __syncthreads();
        int i0 = (b * 256 + t) * 16;
        bool act = i0 < NNZ_;
        if (act) {
#pragma unroll
            for (int c = 0; c < 16; c += 4) {
                int4 e = *reinterpret_cast<const int4*>(E + i0 + c);
                int4 v = *reinterpret_cast<const int4*>(V + i0 + c);
                atomicAdd(&cnt[e.x >> SHE], 1);
                atomicAdd(&cnt[e.y >> SHE], 1);
                atomicAdd(&cnt[e.z >> SHE], 1);
                atomicAdd(&cnt[e.w >> SHE], 1);
                atomicAdd(&cnt[NBKE + (v.x >> SHV)], 1);
                atomicAdd(&cnt[NBKE + (v.y >> SHV)], 1);
                atomicAdd(&cnt[NBKE + (v.z >> SHV)], 1);
                atomicAdd(&cnt[NBKE + (v.w >> SHV)], 1);
            }
        }
        __syncthreads();
        for (int j = t; j < NB; j += 256) {
            int c = cnt[j];
            base[j] = c ? atomicAdd(&gcur[j], c) : 0;
            lcur[j] = 0;
        }
        __syncthreads();
        if (act) {
#pragma unroll
            for (int c = 0; c < 16; c += 4) {
                int4 e = *reinterpret_cast<const int4*>(E + i0 + c);
                int4 v = *reinterpret_cast<const int4*>(V + i0 + c);
                int ev[4] = {e.x, e.y, e.z, e.w};
                int vv[4] = {v.x, v.y, v.z, v.w};
#pragma unroll
                for (int k = 0; k < 4; ++k) {
                    int b1 = ev[k] >> SHE;
                    int p1 = base[b1] + atomicAdd(&lcur[b1], 1);
                    if (p1 < CAP) pairs[(size_t)b1 * CAP + p1] = make_int2(ev[k], vv[k]);
                    int b2 = NBKE + (vv[k] >> SHV);
                    int p2 = base[b2] + atomicAdd(&lcur[b2], 1);
                    if (p2 < CAP) pairs[(size_t)b2 * CAP + p2] = make_int2(vv[k], ev[k]);
                }
            }
        }
    } else if (b < SC1B + WB) {
        int g = (b - SC1B) * 256 + t;
        int n = g >> 8, k = g & 255;
        WT[(size_t)n * 256 + k] = f2bf(W[(size_t)k * 256 + n]);
    } else {
        int i = (b - SC1B - WB) * 256 + t;
        if (i >= N_NODES * D / 8) return;
        const f32x4* p = reinterpret_cast<const f32x4*>(in) + (size_t)i * 2;
        f32x4 a = __builtin_nontemporal_load(p);
        f32x4 c = __builtin_nontemporal_load(p + 1);
        ushortx8 o;
        o[0] = f2bf(a[0]); o[1] = f2bf(a[1]); o[2] = f2bf(a[2]); o[3] = f2bf(a[3]);
        o[4] = f2bf(c[0]); o[5] = f2bf(c[1]); o[6] = f2bf(c[2]); o[7] = f2bf(c[3]);
        *(reinterpret_cast<ushortx8*>(Xbf) + i) = o;
    }
}

// ---------------- fused CSR build: hist + local scan + offC + fill (one block per bucket) ----------------

__global__ void __launch_bounds__(256) build_csr(const int2* __restrict__ pairs,
                                                 const int* __restrict__ gcur,
                                                 int* __restrict__ offC,
                                                 int* __restrict__ adjAll) {
    __shared__ int hist[WKV];          // 2048 (edge buckets use first 512; rest stay 0)
    __shared__ int tsum[256];
    __shared__ int bsum_sh[NB];
    __shared__ int bbase_sh;
    int b = blockIdx.x, t = threadIdx.x;
    bool eside = b < NBKE;
    int kb    = eside ? b * WKE : (b - NBKE) * WKV;
    int nk    = eside ? min(WKE, N_EDGES - kb) : min(WKV, N_NODES - kb);
    int obase = eside ? kb : N_EDGES + kb;
    for (int j = t; j < WKV; j += 256) hist[j] = 0;
    if (t < NB) bsum_sh[t] = gcur[t];
    __syncthreads();
    if (t == 0) {
        int s = 0;
        for (int j = 0; j < b; ++j) s += bsum_sh[j];
        bbase_sh = s;
    }
    int n = min(gcur[b], CAP);
    const int2* p = pairs + (size_t)b * CAP;
    for (int i = t; i < n; i += 256) {
        atomicAdd(&hist[p[i].x - kb], 1);
    }
    __syncthreads();
    int bbase = bbase_sh;
    // blocked exclusive scan over 2048 entries, 8 per thread (uniform, compile-time)
    int j0 = t * 8;
    int s = 0;
#pragma unroll
    for (int j = 0; j < 8; ++j) s += hist[j0 + j];
    tsum[t] = s;
    __syncthreads();
    for (int o = 1; o < 256; o <<= 1) {
        int u = (t >= o) ? tsum[t - o] : 0;
        __syncthreads();
        tsum[t] += u;
        __syncthreads();
    }
    int excl = tsum[t] - s;
    int curv[8];
#pragma unroll
    for (int j = 0; j < 8; ++j) {
        int h = hist[j0 + j];
        curv[j] = bbase + excl;
        if (j0 + j < nk) offC[obase + j0 + j] = bbase + excl;
        excl += h;
    }
    __syncthreads();                   // all hist reads done
#pragma unroll
    for (int j = 0; j < 8; ++j) hist[j0 + j] = curv[j];   // global cursor
    if (b == NB - 1 && t == 0) offC[NTOT] = bbase + n;
    __syncthreads();
    for (int i = t; i < n; i += 256) {
        int2 pr = p[i];
        int slot = atomicAdd(&hist[pr.x - kb], 1);
        adjAll[slot] = pr.y;
    }
}

// ---------------- shared gather core: lane-parallel index prefetch + shuffle broadcast ----------------

__device__ __forceinline__ void gather_rows(const ushort* __restrict__ src,
                                            const int* __restrict__ adjAll,
                                            int b, int cnt, int half, int col8,
                                            float a[8], int lane) {
    for (int c0 = 0; c0 < cnt; c0 += 64) {
        int rem = cnt - c0;                        // > 0
        int li = c0 + min(lane, rem - 1);
        int myidx = adjAll[b + li];                // one coalesced load per chunk
        int lim = min(rem, 64);
        for (int j0 = 0; j0 < lim; j0 += 8) {
            int r0 = __shfl(myidx, j0 + 0 + half, 64);
            int r1 = __shfl(myidx, j0 + 2 + half, 64);
            int r2 = __shfl(myidx, j0 + 4 + half, 64);
            int r3 = __shfl(myidx, j0 + 6 + half, 64);
            ushortx8 x0 = *reinterpret_cast<const ushortx8*>(src + (size_t)r0 * D + col8);
            ushortx8 x1 = *reinterpret_cast<const ushortx8*>(src + (size_t)r1 * D + col8);
            ushortx8 x2 = *reinterpret_cast<const ushortx8*>(src + (size_t)r2 * D + col8);
            ushortx8 x3 = *reinterpret_cast<const ushortx8*>(src + (size_t)r3 * D + col8);
            if (j0 + 0 + half < lim) {
#pragma unroll
                for (int k = 0; k < 8; ++k) a[k] += bf2f(x0[k]);
            }
            if (j0 + 2 + half < lim) {
#pragma unroll
                for (int k = 0; k < 8; ++k) a[k] += bf2f(x1[k]);
            }
            if (j0 + 4 + half < lim) {
#pragma unroll
                for (int k = 0; k < 8; ++k) a[k] += bf2f(x2[k]);
            }
            if (j0 + 6 + half < lim) {
#pragma unroll
                for (int k = 0; k < 8; ++k) a[k] += bf2f(x3[k]);
            }
        }
    }
}

// ---------------- phase 1: edge aggregation (one wave per edge) ----------------

__global__ void edge_agg(const ushort* __restrict__ Xbf, const int* __restrict__ adjAll,
                         const int* __restrict__ offC, const float* __restrict__ degE,
                         ushort* __restrict__ Ye) {
    int gid = blockIdx.x * blockDim.x + threadIdx.x;
    int edge = gid >> 6;
    int lane = gid & 63;
    if (edge >= N_EDGES) return;
    int half = lane >> 5;
    int col8 = (lane & 31) * 8;
    int b = offC[edge], e = offC[edge + 1];
    int cnt = e - b;
    float a[8] = {0.f, 0.f, 0.f, 0.f, 0.f, 0.f, 0.f, 0.f};
    gather_rows(Xbf, adjAll, b, cnt, half, col8, a, lane);
#pragma unroll
    for (int k = 0; k < 8; ++k) a[k] += __shfl_xor(a[k], 32, 64);
    float s = degE[edge] / (float)(cnt > 1 ? cnt : 1);
    int k0 = half * 4;
    ushortx4 o;
    o[0] = f2bf(a[k0 + 0] * s); o[1] = f2bf(a[k0 + 1] * s);
    o[2] = f2bf(a[k0 + 2] * s); o[3] = f2bf(a[k0 + 3] * s);
    *reinterpret_cast<ushortx4*>(Ye + (size_t)edge * D + col8 + k0) = o;
}

// ---------------- phase 2: MFMA GEMM  Ze[MP,256] = Ye[MP,256] @ W  (bf16, LDS-free) ----------------

__global__ void __launch_bounds__(256) gemm_mfma(const ushort* __restrict__ A,
                                                 const ushort* __restrict__ WT,
                                                 ushort* __restrict__ C, int M) {
    int wid  = threadIdx.x >> 6;
    int lane = threadIdx.x & 63;
    int row0 = blockIdx.x * 64 + wid * 16;
    int lr  = lane & 15;
    int lk8 = (lane >> 4) * 8;
    f32x4 acc[16];
#pragma unroll
    for (int t = 0; t < 16; ++t) acc[t] = (f32x4){0.f, 0.f, 0.f, 0.f};
    int arow = row0 + lr;
    if (arow >= M) arow = M - 1;
    const ushort* aptr = A + (size_t)arow * D;
#pragma unroll
    for (int k0 = 0; k0 < D; k0 += 32) {
        short8 af = *reinterpret_cast<const short8*>(aptr + k0 + lk8);
#pragma unroll
        for (int t = 0; t < 16; ++t) {
            short8 bf = *reinterpret_cast<const short8*>(
                WT + (size_t)(t * 16 + lr) * D + k0 + lk8);
            acc[t] = __builtin_amdgcn_mfma_f32_16x16x32_bf16(af, bf, acc[t], 0, 0, 0);
        }
    }
    int crow = row0 + (lane >> 4) * 4;
#pragma unroll
    for (int t = 0; t < 16; ++t) {
        int ccol = t * 16 + lr;
#pragma unroll
        for (int r = 0; r < 4; ++r) {
            int rr = crow + r;
            if (rr < M) C[(size_t)rr * D + ccol] = f2bf(acc[t][r]);
        }
    }
}

// ---------------- phase 3: node aggregation (one wave per node, NT store) ----------------

__global__ void node_agg(const ushort* __restrict__ Ze, const int* __restrict__ adjAll,
                         const int* __restrict__ offC, const float* __restrict__ degV,
                         const float* __restrict__ bias, float* __restrict__ out) {
    int gid = blockIdx.x * blockDim.x + threadIdx.x;
    int node = gid >> 6;
    int lane = gid & 63;
    if (node >= N_NODES) return;
    int half = lane >> 5;
    int col8 = (lane & 31) * 8;
    int b = offC[N_EDGES + node], e = offC[N_EDGES + node + 1];
    int cnt = e - b;
    float a[8] = {0.f, 0.f, 0.f, 0.f, 0.f, 0.f, 0.f, 0.f};
    gather_rows(Ze, adjAll, b, cnt, half, col8, a, lane);
#pragma unroll
    for (int k = 0; k < 8; ++k) a[k] += __shfl_xor(a[k], 32, 64);
    float dv = degV[node];
    int k0 = half * 4;
    int c = col8 + k0;
    f32x4 b4 = *reinterpret_cast<const f32x4*>(bias + c);
    f32x4 o;
    o[0] = a[k0 + 0] * dv + b4[0];
    o[1] = a[k0 + 1] * dv + b4[1];
    o[2] = a[k0 + 2] * dv + b4[2];
    o[3] = a[k0 + 3] * dv + b4[3];
    __builtin_nontemporal_store(o, reinterpret_cast<f32x4*>(out + (size_t)node * D + c));
}

// ---------------- launch ----------------

extern "C" void kernel_launch(void* const* d_in, const int* in_sizes, int n_in,
                              void* d_out, int out_size, void* d_ws, size_t ws_size,
                              hipStream_t stream) {
    const float* input  = (const float*)d_in[0];
    const int*   V      = (const int*)d_in[1];
    const int*   E      = (const int*)d_in[2];
    const float* degV   = (const float*)d_in[3];
    const float* degE   = (const float*)d_in[4];
    const float* weight = (const float*)d_in[5];
    const float* bias   = (const float*)d_in[6];
    float* out = (float*)d_out;

    int* gcur   = (int*)d_ws;                       // 128 (98 used)
    int* offC   = gcur + 128;                       // NTOT+1
    int* adjAll = offC + (NTOT + 1);                // 2*NNZ
    uintptr_t p = (uintptr_t)(adjAll + 2 * NNZ_);
    p = (p + 255) & ~(uintptr_t)255;
    ushort* Xbf = (ushort*)p;                       // N_NODES*D   (51.2 MB)
    ushort* Ye  = Xbf + (size_t)N_NODES * D;        // MP*D        (12.8 MB)
    ushort* Ze  = Ye + (size_t)MP * D;              // MP*D        (12.8 MB)
    ushort* WT  = Ze + (size_t)MP * D;              // 256*256     (128 KB)
    int2* pairs = (int2*)Ye;                        // 19.3MB, aliases Ye+Ze (dead until edge_agg)

    hipMemsetAsync(gcur, 0, 128 * sizeof(int), stream);

    front_kernel<<<SC1B + WB + CB, 256, 0, stream>>>(V, E, gcur, pairs,
                                                     weight, WT, input, Xbf);

    build_csr<<<NB, 256, 0, stream>>>(pairs, gcur, offC, adjAll);

    edge_agg<<<(N_EDGES * 64 + 255) / 256, 256, 0, stream>>>(Xbf, adjAll, offC, degE, Ye);

    gemm_mfma<<<MP / 64, 256, 0, stream>>>(Ye, WT, Ze, N_EDGES);

    node_agg<<<(N_NODES * 64 + 255) / 256, 256, 0, stream>>>(Ze, adjAll, offC, degV, bias, out);
}